// Round 4
// baseline (1836.910 us; speedup 1.0000x reference)
//
#include <hip/hip_runtime.h>
#include <hip/hip_bf16.h>

// Problem constants
constexpr int B  = 8;
constexpr int N  = 2048;
constexpr int Fv = 3;      // vector axis F
constexpr int Dd = 256;    // D
constexpr int QK = 512;
constexpr int Vd = 512;
constexpr int Hh = 8;
constexpr int Qq = 64;
constexpr int DH = 64;     // QK/H
constexpr int DV = 64;     // V/H
constexpr int TOK = 4;     // tokens per block in fused kernel

constexpr float EPS  = 1e-6f;
constexpr float NEG  = 0.2f;
constexpr float LNE  = 1e-6f;

// ---------------------------------------------------------------------------
// Fused kernel: per 4 tokens (b,n):
//   kv    = EVN(x @ w_kv)                       (kept in LDS, f32)
//   kinv  = einsum('fd,f->d', kv, mean_d(kv))   (kept in LDS, f32)
//   k     = LN(kinv @ wk)   -> kbuf [h][b][n][e]
//   v     = kv @ wv         -> vbuf [h][b][n][f][e]
// Thread t owns output columns {t, t+256} of every 512-wide matmul.
// ---------------------------------------------------------------------------
__global__ __launch_bounds__(256) void k_fused1(
    const float* __restrict__ x,   const float* __restrict__ w_kv,
    const float* __restrict__ w1a, const float* __restrict__ b1a,
    const float* __restrict__ w1b, const float* __restrict__ b1b,
    const float* __restrict__ wk,  const float* __restrict__ lks,
    const float* __restrict__ lkb, const float* __restrict__ wv,
    float* __restrict__ kbuf, float* __restrict__ vbuf)
{
    __shared__ float xs[TOK * Fv * Dd];     // 3072 f; reused as kinv later
    __shared__ float kvs[TOK][Fv * QK];     // 6144 f
    __shared__ float norm_s[TOK][QK];       // 2048 f
    __shared__ float h_s[TOK][256];         // 1024 f
    __shared__ float red[TOK][3][4];

    const int t = threadIdx.x;
    const long bn0 = (long)blockIdx.x * TOK;

    // ---- load x for 4 tokens (contiguous) ----
    const float* xp = x + bn0 * (Fv * Dd);
    for (int i = t; i < TOK * Fv * Dd; i += 256) xs[i] = xp[i];
    __syncthreads();

    // ---- kv_pre = x @ w_kv ----
    float a[TOK][6];
    #pragma unroll
    for (int k = 0; k < TOK; ++k)
        #pragma unroll
        for (int j = 0; j < 6; ++j) a[k][j] = 0.f;

    for (int d = 0; d < Dd; ++d) {
        const float w0 = w_kv[d * QK + t];
        const float w1 = w_kv[d * QK + t + 256];
        #pragma unroll
        for (int k = 0; k < TOK; ++k) {
            const float x0 = xs[k * 768 + d];
            const float x1 = xs[k * 768 + 256 + d];
            const float x2 = xs[k * 768 + 512 + d];
            a[k][0] += x0 * w0; a[k][1] += x1 * w0; a[k][2] += x2 * w0;
            a[k][3] += x0 * w1; a[k][4] += x1 * w1; a[k][5] += x2 * w1;
        }
    }

    // ---- norms over F ----
    float nrm0[TOK], nrm1[TOK];
    #pragma unroll
    for (int k = 0; k < TOK; ++k) {
        nrm0[k] = sqrtf(a[k][0] * a[k][0] + a[k][1] * a[k][1] + a[k][2] * a[k][2]);
        nrm1[k] = sqrtf(a[k][3] * a[k][3] + a[k][4] * a[k][4] + a[k][5] * a[k][5]);
        norm_s[k][t]       = nrm0[k];
        norm_s[k][t + 256] = nrm1[k];
    }
    __syncthreads();

    // ---- h = leaky_relu((norm+EPS) @ w1a + b1a) ----
    float hacc[TOK];
    {
        const float bb = b1a[t];
        #pragma unroll
        for (int k = 0; k < TOK; ++k) hacc[k] = bb;
    }
    for (int d = 0; d < QK; ++d) {
        const float w = w1a[d * 256 + t];
        #pragma unroll
        for (int k = 0; k < TOK; ++k) hacc[k] += (norm_s[k][d] + EPS) * w;
    }
    #pragma unroll
    for (int k = 0; k < TOK; ++k)
        h_s[k][t] = hacc[k] > 0.f ? hacc[k] : NEG * hacc[k];
    __syncthreads();

    // ---- g = h @ w1b + b1b ----
    float g0[TOK], g1[TOK];
    {
        const float bb0 = b1b[t], bb1 = b1b[t + 256];
        #pragma unroll
        for (int k = 0; k < TOK; ++k) { g0[k] = bb0; g1[k] = bb1; }
    }
    for (int j = 0; j < 256; ++j) {
        const float w0 = w1b[j * QK + t];
        const float w1 = w1b[j * QK + t + 256];
        #pragma unroll
        for (int k = 0; k < TOK; ++k) {
            const float hv = h_s[k][j];
            g0[k] += hv * w0;
            g1[k] += hv * w1;
        }
    }

    // ---- EVN gate; kv -> LDS; per-f column-sum partials ----
    float m0[TOK], m1[TOK], m2[TOK];
    #pragma unroll
    for (int k = 0; k < TOK; ++k) {
        const float s0 = (nrm0[k] <= EPS) ? 1.f : g0[k] / (nrm0[k] + EPS);
        const float s1 = (nrm1[k] <= EPS) ? 1.f : g1[k] / (nrm1[k] + EPS);
        a[k][0] *= s0; a[k][1] *= s0; a[k][2] *= s0;
        a[k][3] *= s1; a[k][4] *= s1; a[k][5] *= s1;
        kvs[k][0 * QK + t]       = a[k][0];
        kvs[k][1 * QK + t]       = a[k][1];
        kvs[k][2 * QK + t]       = a[k][2];
        kvs[k][0 * QK + t + 256] = a[k][3];
        kvs[k][1 * QK + t + 256] = a[k][4];
        kvs[k][2 * QK + t + 256] = a[k][5];
        m0[k] = a[k][0] + a[k][3];
        m1[k] = a[k][1] + a[k][4];
        m2[k] = a[k][2] + a[k][5];
    }
    #pragma unroll
    for (int k = 0; k < TOK; ++k) {
        for (int off = 32; off; off >>= 1) {
            m0[k] += __shfl_down(m0[k], off);
            m1[k] += __shfl_down(m1[k], off);
            m2[k] += __shfl_down(m2[k], off);
        }
        if ((t & 63) == 0) {
            red[k][0][t >> 6] = m0[k];
            red[k][1][t >> 6] = m1[k];
            red[k][2][t >> 6] = m2[k];
        }
    }
    __syncthreads();

    // ---- kinv = sum_f kv[f,:] * mean[f]  -> store into xs (x is dead) ----
    constexpr float inv512 = 1.f / 512.f;
    #pragma unroll
    for (int k = 0; k < TOK; ++k) {
        const float mean0 = (red[k][0][0] + red[k][0][1] + red[k][0][2] + red[k][0][3]) * inv512;
        const float mean1 = (red[k][1][0] + red[k][1][1] + red[k][1][2] + red[k][1][3]) * inv512;
        const float mean2 = (red[k][2][0] + red[k][2][1] + red[k][2][2] + red[k][2][3]) * inv512;
        xs[k * 768 + t]       = a[k][0] * mean0 + a[k][1] * mean1 + a[k][2] * mean2;
        xs[k * 768 + t + 256] = a[k][3] * mean0 + a[k][4] * mean1 + a[k][5] * mean2;
    }
    __syncthreads();

    // ---- k = LN(kinv @ wk) per head ----
    {
        float ka0[TOK], ka1[TOK];
        #pragma unroll
        for (int k = 0; k < TOK; ++k) { ka0[k] = 0.f; ka1[k] = 0.f; }
        for (int d = 0; d < QK; ++d) {
            const float w0 = wk[d * QK + t];
            const float w1 = wk[d * QK + t + 256];
            #pragma unroll
            for (int k = 0; k < TOK; ++k) {
                const float c = xs[k * 768 + d];
                ka0[k] += c * w0;
                ka1[k] += c * w1;
            }
        }
        const int e = t & 63;
        const int h0 = t >> 6, h1 = h0 + 4;
        const float sc = lks[e], bi = lkb[e];
        #pragma unroll
        for (int k = 0; k < TOK; ++k) {
            float s0 = ka0[k], q0 = ka0[k] * ka0[k];
            float s1 = ka1[k], q1 = ka1[k] * ka1[k];
            for (int off = 32; off; off >>= 1) {
                s0 += __shfl_down(s0, off); q0 += __shfl_down(q0, off);
                s1 += __shfl_down(s1, off); q1 += __shfl_down(q1, off);
            }
            s0 = __shfl(s0, 0); q0 = __shfl(q0, 0);
            s1 = __shfl(s1, 0); q1 = __shfl(q1, 0);
            const float mean0 = s0 * (1.f / 64.f), var0 = q0 * (1.f / 64.f) - mean0 * mean0;
            const float mean1 = s1 * (1.f / 64.f), var1 = q1 * (1.f / 64.f) - mean1 * mean1;
            const float r0 = (ka0[k] - mean0) * rsqrtf(var0 + LNE) * sc + bi;
            const float r1 = (ka1[k] - mean1) * rsqrtf(var1 + LNE) * sc + bi;
            kbuf[((long)h0 * B * N + bn0 + k) * DH + e] = r0;
            kbuf[((long)h1 * B * N + bn0 + k) * DH + e] = r1;
        }
    }

    // ---- v = kv @ wv ----
    {
        float va[TOK][6];
        #pragma unroll
        for (int k = 0; k < TOK; ++k)
            #pragma unroll
            for (int j = 0; j < 6; ++j) va[k][j] = 0.f;
        for (int d = 0; d < QK; ++d) {
            const float w0 = wv[d * QK + t];
            const float w1 = wv[d * QK + t + 256];
            #pragma unroll
            for (int k = 0; k < TOK; ++k) {
                const float c0 = kvs[k][d];
                const float c1 = kvs[k][QK + d];
                const float c2 = kvs[k][2 * QK + d];
                va[k][0] += c0 * w0; va[k][1] += c1 * w0; va[k][2] += c2 * w0;
                va[k][3] += c0 * w1; va[k][4] += c1 * w1; va[k][5] += c2 * w1;
            }
        }
        const int e = t & 63;
        const int h0 = t >> 6, h1 = h0 + 4;
        #pragma unroll
        for (int k = 0; k < TOK; ++k)
            #pragma unroll
            for (int f = 0; f < Fv; ++f) {
                vbuf[((long)h0 * B * N + bn0 + k) * (Fv * DV) + f * DV + e] = va[k][f];
                vbuf[((long)h1 * B * N + bn0 + k) * (Fv * DV) + f * DV + e] = va[k][3 + f];
            }
    }
}

// ---------------------------------------------------------------------------
// q = LN(lq @ wq) per head, write [h][q][e] f32. One block per qi.
// ---------------------------------------------------------------------------
__global__ __launch_bounds__(256) void k_qproj(
    const float* __restrict__ lq, const float* __restrict__ wq,
    const float* __restrict__ lns, const float* __restrict__ lnb,
    float* __restrict__ qout)
{
    __shared__ float cs[QK];
    const int t = threadIdx.x;
    const int qi = blockIdx.x;
    const float* cp = lq + (long)qi * QK;
    for (int i = t; i < QK; i += 256) cs[i] = cp[i];
    __syncthreads();

    float a0 = 0, a1 = 0;
    #pragma unroll 4
    for (int d = 0; d < QK; ++d) {
        const float c = cs[d];
        a0 += c * wq[d * QK + t];
        a1 += c * wq[d * QK + t + 256];
    }
    float s0 = a0, q0 = a0 * a0, s1 = a1, q1 = a1 * a1;
    for (int off = 32; off; off >>= 1) {
        s0 += __shfl_down(s0, off); q0 += __shfl_down(q0, off);
        s1 += __shfl_down(s1, off); q1 += __shfl_down(q1, off);
    }
    s0 = __shfl(s0, 0); q0 = __shfl(q0, 0);
    s1 = __shfl(s1, 0); q1 = __shfl(q1, 0);
    const float mean0 = s0 * (1.f / 64.f), var0 = q0 * (1.f / 64.f) - mean0 * mean0;
    const float mean1 = s1 * (1.f / 64.f), var1 = q1 * (1.f / 64.f) - mean1 * mean1;
    const int e = t & 63;
    const float sc = lns[e], bi = lnb[e];
    const float r0 = (a0 - mean0) * rsqrtf(var0 + LNE) * sc + bi;
    const float r1 = (a1 - mean1) * rsqrtf(var1 + LNE) * sc + bi;
    const int h0 = t >> 6, h1 = h0 + 4;
    qout[((long)h0 * Qq + qi) * DH + e] = r0;
    qout[((long)h1 * Qq + qi) * DH + e] = r1;
}

// ---------------------------------------------------------------------------
// attn row = softmax( (q . k) / 8 ) over n.  One block per (h,b,qi).
// ---------------------------------------------------------------------------
__global__ __launch_bounds__(256) void k_attn(
    const float* __restrict__ qv, const float* __restrict__ kf,
    float* __restrict__ attn)
{
    __shared__ float qs[DH];
    __shared__ float ks[128 * 65];
    __shared__ float sc[N];
    __shared__ float red[4];

    const int t = threadIdx.x;
    const int idx = blockIdx.x;                  // ((h*B+b)*Qq + qi)
    const int qi = idx & (Qq - 1);
    const int hb = idx / Qq;
    if (t < DH) qs[t] = qv[((long)(hb / B) * Qq + qi) * DH + t];
    const float* kp = kf + (long)hb * N * DH;

    for (int T = 0; T < N / 128; ++T) {
        __syncthreads();
        for (int i = t; i < 128 * DH; i += 256) {
            int n = i >> 6, e = i & 63;
            ks[n * 65 + e] = kp[(long)T * 128 * DH + i];
        }
        __syncthreads();
        if (t < 128) {
            float s = 0;
            #pragma unroll 8
            for (int e = 0; e < DH; ++e) s += qs[e] * ks[t * 65 + e];
            sc[T * 128 + t] = s * 0.125f;
        }
    }
    __syncthreads();

    float lm = -1e30f;
    for (int i = t; i < N; i += 256) lm = fmaxf(lm, sc[i]);
    for (int off = 32; off; off >>= 1) lm = fmaxf(lm, __shfl_down(lm, off));
    if ((t & 63) == 0) red[t >> 6] = lm;
    __syncthreads();
    const float m = fmaxf(fmaxf(red[0], red[1]), fmaxf(red[2], red[3]));
    __syncthreads();
    float ls = 0;
    for (int i = t; i < N; i += 256) {
        const float p = __expf(sc[i] - m);
        sc[i] = p;
        ls += p;
    }
    for (int off = 32; off; off >>= 1) ls += __shfl_down(ls, off);
    if ((t & 63) == 0) red[t >> 6] = ls;
    __syncthreads();
    const float inv = 1.f / (red[0] + red[1] + red[2] + red[3]);
    float* ap = attn + (long)idx * N;
    for (int i = t; i < N; i += 256) ap[i] = sc[i] * inv;
}

// ---------------------------------------------------------------------------
// resiT[b][q][f][h*64+e] = sum_n attn[h,b,q,n] * v[h,b,n,f,e]
// One block per (h,b,qtile-of-8). 192 threads (one per (f,e)).
// ---------------------------------------------------------------------------
__global__ __launch_bounds__(192) void k_pv(
    const float* __restrict__ attn, const float* __restrict__ v,
    float* __restrict__ resiT)
{
    __shared__ float as[8][256];
    const int t = threadIdx.x;
    const int idx = blockIdx.x;          // hb*8 + qt
    const int qt = idx & 7;
    const int hb = idx >> 3;
    const int h = hb / B, b = hb % B;

    float acc[8] = {0, 0, 0, 0, 0, 0, 0, 0};
    const float* vp = v + (long)hb * N * (Fv * DV);
    const float* ap = attn + ((long)hb * Qq + qt * 8) * N;

    for (int c = 0; c < N / 256; ++c) {
        __syncthreads();
        for (int i = t; i < 8 * 256; i += 192) {
            int qr = i >> 8, j = i & 255;
            as[qr][j] = ap[(long)qr * N + c * 256 + j];
        }
        __syncthreads();
        #pragma unroll 4
        for (int j = 0; j < 256; ++j) {
            const float vv = vp[(long)(c * 256 + j) * (Fv * DV) + t];
            #pragma unroll
            for (int qr = 0; qr < 8; ++qr) acc[qr] += as[qr][j] * vv;
        }
    }
    const int f = t / DV, e = t % DV;
    #pragma unroll
    for (int qr = 0; qr < 8; ++qr) {
        const int q = qt * 8 + qr;
        resiT[(((long)b * Qq + q) * Fv + f) * Vd + h * DV + e] = acc[qr];
    }
}

// ---------------------------------------------------------------------------
// out = EVN2(resiT @ w_out), fp32 store (reference output dtype is float32).
// One block per (b,q).
// ---------------------------------------------------------------------------
__global__ __launch_bounds__(256) void k_out(
    const float* __restrict__ resiT, const float* __restrict__ w_out,
    const float* __restrict__ w2a, const float* __restrict__ b2a,
    const float* __restrict__ w2b, const float* __restrict__ b2b,
    float* __restrict__ out)
{
    __shared__ float rs[Fv * Vd];   // 1536
    __shared__ float norm_s[Vd];
    __shared__ float h_s[256];

    const int t = threadIdx.x;
    const long bq = blockIdx.x;
    const float* rp = resiT + bq * (Fv * Vd);
    for (int i = t; i < Fv * Vd; i += 256) rs[i] = rp[i];
    __syncthreads();

    float a0 = 0, a1 = 0, a2 = 0, a3 = 0, a4 = 0, a5 = 0;
    #pragma unroll 4
    for (int d = 0; d < Vd; ++d) {
        const float w0 = w_out[d * Vd + t];
        const float w1 = w_out[d * Vd + t + 256];
        const float x0 = rs[d], x1 = rs[Vd + d], x2 = rs[2 * Vd + d];
        a0 += x0 * w0; a1 += x1 * w0; a2 += x2 * w0;
        a3 += x0 * w1; a4 += x1 * w1; a5 += x2 * w1;
    }
    const float nrm0 = sqrtf(a0 * a0 + a1 * a1 + a2 * a2);
    const float nrm1 = sqrtf(a3 * a3 + a4 * a4 + a5 * a5);
    norm_s[t] = nrm0;
    norm_s[t + 256] = nrm1;
    __syncthreads();

    float hacc = b2a[t];
    #pragma unroll 4
    for (int d = 0; d < Vd; ++d) hacc += (norm_s[d] + EPS) * w2a[d * 256 + t];
    h_s[t] = hacc > 0.f ? hacc : NEG * hacc;
    __syncthreads();

    float g0 = b2b[t], g1 = b2b[t + 256];
    #pragma unroll 4
    for (int j = 0; j < 256; ++j) {
        const float hv = h_s[j];
        g0 += hv * w2b[j * Vd + t];
        g1 += hv * w2b[j * Vd + t + 256];
    }
    const float s0 = (nrm0 <= EPS) ? 1.f : g0 / (nrm0 + EPS);
    const float s1 = (nrm1 <= EPS) ? 1.f : g1 / (nrm1 + EPS);

    float* op = out + bq * (Fv * Vd);
    op[0 * Vd + t]       = a0 * s0;
    op[1 * Vd + t]       = a1 * s0;
    op[2 * Vd + t]       = a2 * s0;
    op[0 * Vd + t + 256] = a3 * s1;
    op[1 * Vd + t + 256] = a4 * s1;
    op[2 * Vd + t + 256] = a5 * s1;
}

// ---------------------------------------------------------------------------
extern "C" void kernel_launch(void* const* d_in, const int* in_sizes, int n_in,
                              void* d_out, int out_size, void* d_ws, size_t ws_size,
                              hipStream_t stream)
{
    const float* x    = (const float*)d_in[0];
    const float* lq   = (const float*)d_in[1];
    const float* w_kv = (const float*)d_in[2];
    const float* w1a  = (const float*)d_in[3];
    const float* b1a  = (const float*)d_in[4];
    const float* w1b  = (const float*)d_in[5];
    const float* b1b  = (const float*)d_in[6];
    const float* wq   = (const float*)d_in[7];
    const float* wk   = (const float*)d_in[8];
    const float* wv   = (const float*)d_in[9];
    const float* lqs  = (const float*)d_in[10];
    const float* lqb  = (const float*)d_in[11];
    const float* lks  = (const float*)d_in[12];
    const float* lkb  = (const float*)d_in[13];
    const float* wo   = (const float*)d_in[14];
    const float* w2a  = (const float*)d_in[15];
    const float* b2a  = (const float*)d_in[16];
    const float* w2b  = (const float*)d_in[17];
    const float* b2b  = (const float*)d_in[18];

    char* ws = (char*)d_ws;
    // Workspace layout (bytes), all f32:
    //   kbuf  [H*B*N*DH]   =  33,554,432
    //   qbuf  [H*Q*DH]     =     131,072
    //   vbuf  [H*B*N*F*DV] = 100,663,296
    //   attn  [H*B*Q*N]    =  33,554,432
    //   resiT [B*Q*F*V]    =   3,145,728   (total ~171 MB)
    float* kbuf  = (float*)(ws + 0);
    float* qbuf  = (float*)(ws + 33554432L);
    float* vbuf  = (float*)(ws + 33685504L);
    float* attn  = (float*)(ws + 134348800L);
    float* resiT = (float*)(ws + 167903232L);
    float* out   = (float*)d_out;

    k_fused1<<<B * N / TOK, 256, 0, stream>>>(x, w_kv, w1a, b1a, w1b, b1b,
                                              wk, lks, lkb, wv, kbuf, vbuf);
    k_qproj <<<Qq,          256, 0, stream>>>(lq, wq, lqs, lqb, qbuf);
    k_attn  <<<Hh * B * Qq, 256, 0, stream>>>(qbuf, kbuf, attn);
    k_pv    <<<Hh * B * 8,  192, 0, stream>>>(attn, vbuf, resiT);
    k_out   <<<B * Qq,      256, 0, stream>>>(resiT, wo, w2a, b2a, w2b, b2b, out);
}

// Round 6
// 934.324 us; speedup vs baseline: 1.9660x; 1.9660x over previous
//
#include <hip/hip_runtime.h>
#include <hip/hip_bf16.h>

typedef _Float16 f16;
typedef __attribute__((ext_vector_type(8))) _Float16 f16x8;
typedef __attribute__((ext_vector_type(4))) _Float16 f16x4;
typedef __attribute__((ext_vector_type(2))) _Float16 f16x2;
typedef __attribute__((ext_vector_type(4))) float floatx4;

// Problem constants
constexpr int B  = 8;
constexpr int N  = 2048;
constexpr int Fv = 3;
constexpr int Dd = 256;
constexpr int QK = 512;
constexpr int Vd = 512;
constexpr int Hh = 8;
constexpr int Qq = 64;
constexpr int DH = 64;
constexpr int NT = B * N;          // 16384 tokens
constexpr float EPS = 1e-6f;
constexpr float NEG = 0.2f;
constexpr float LNE = 1e-6f;

#define DEV static __device__ __forceinline__
DEV void split(float v, f16& h, f16& l) { h = (f16)v; l = (f16)(v - (float)h); }

// ---------------------------------------------------------------------------
// Split-fp16 3-mul GEMM (effective fp32 accuracy): C = A[M,K] @ B[K,N]
// A as (Ah,Al) f16 pairs (ASRC=0) or fp32 split on the fly (ASRC=1).
// Bt = B^T row-major [N,K] as (Bh,Bl) pairs.
// Block 256 thr = 4 waves; tile 128M x 64N; wave = 32 rows x 64 cols.
// EPI: 0 pair store (kv_pre)        1 +bias,leaky -> pair (hb)
//      2 +bias -> f32 (g)           3 per-64col LN -> f32 kbuf [h][tok][64]
//      5 PV2: rows h*1536.., store f32 resiT[(b,q,f)][512] at col h*64+
// ---------------------------------------------------------------------------
template<int ASRC, int EPI>
__global__ __launch_bounds__(256) void k_gemm3(
    const float* __restrict__ A32,
    const f16* __restrict__ Ah, const f16* __restrict__ Al,
    const f16* __restrict__ Bh, const f16* __restrict__ Bl,
    int Ndim, int Kdim, void* __restrict__ C1, void* __restrict__ C2,
    const float* __restrict__ e0, const float* __restrict__ e1)
{
    __shared__ __align__(16) f16 Ash[128][72];
    __shared__ __align__(16) f16 Asl[128][72];
    __shared__ __align__(16) f16 Bsh[64][72];
    __shared__ __align__(16) f16 Bsl[64][72];

    const int t = threadIdx.x;
    long row0; int col0, boff;
    if (EPI == 5) { row0 = (long)blockIdx.y * 1536 + (long)blockIdx.x * 128; col0 = 0; boff = blockIdx.y * 64; }
    else          { row0 = (long)blockIdx.x * 128; col0 = blockIdx.y * 64; boff = 0; }

    floatx4 acc0[4], acc1[4];
    #pragma unroll
    for (int nt = 0; nt < 4; ++nt)
        #pragma unroll
        for (int j = 0; j < 4; ++j) { acc0[nt][j] = 0.f; acc1[nt][j] = 0.f; }

    const int L = t & 63, w = t >> 6;
    const int kq = (L >> 4) << 3;

    for (int k0 = 0; k0 < Kdim; k0 += 64) {
        if constexpr (ASRC == 1) {
            #pragma unroll
            for (int j = 0; j < 8; ++j) {
                const int i = t + j * 256;
                const int r = i >> 4, c4 = (i & 15) << 2;
                const floatx4 v = *(const floatx4*)&A32[(row0 + r) * Kdim + k0 + c4];
                f16x4 h4, l4;
                #pragma unroll
                for (int m = 0; m < 4; ++m) { h4[m] = (f16)v[m]; l4[m] = (f16)(v[m] - (float)h4[m]); }
                *(f16x4*)&Ash[r][c4] = h4;
                *(f16x4*)&Asl[r][c4] = l4;
            }
        } else {
            #pragma unroll
            for (int j = 0; j < 4; ++j) {
                const int i = t + j * 256;
                const int r = i >> 3, c8 = (i & 7) << 3;
                *(f16x8*)&Ash[r][c8] = *(const f16x8*)&Ah[(row0 + r) * (long)Kdim + k0 + c8];
                *(f16x8*)&Asl[r][c8] = *(const f16x8*)&Al[(row0 + r) * (long)Kdim + k0 + c8];
            }
        }
        #pragma unroll
        for (int j = 0; j < 2; ++j) {
            const int i = t + j * 256;
            const int r = i >> 3, c8 = (i & 7) << 3;
            *(f16x8*)&Bsh[r][c8] = *(const f16x8*)&Bh[(long)(boff + col0 + r) * Kdim + k0 + c8];
            *(f16x8*)&Bsl[r][c8] = *(const f16x8*)&Bl[(long)(boff + col0 + r) * Kdim + k0 + c8];
        }
        __syncthreads();
        #pragma unroll
        for (int kk = 0; kk < 64; kk += 32) {
            const f16x8 ah0 = *(const f16x8*)&Ash[w * 32 + (L & 15)][kk + kq];
            const f16x8 al0 = *(const f16x8*)&Asl[w * 32 + (L & 15)][kk + kq];
            const f16x8 ah1 = *(const f16x8*)&Ash[w * 32 + 16 + (L & 15)][kk + kq];
            const f16x8 al1 = *(const f16x8*)&Asl[w * 32 + 16 + (L & 15)][kk + kq];
            #pragma unroll
            for (int nt = 0; nt < 4; ++nt) {
                const f16x8 bh = *(const f16x8*)&Bsh[nt * 16 + (L & 15)][kk + kq];
                const f16x8 bl = *(const f16x8*)&Bsl[nt * 16 + (L & 15)][kk + kq];
                acc0[nt] = __builtin_amdgcn_mfma_f32_16x16x32_f16(ah0, bh, acc0[nt], 0, 0, 0);
                acc0[nt] = __builtin_amdgcn_mfma_f32_16x16x32_f16(ah0, bl, acc0[nt], 0, 0, 0);
                acc0[nt] = __builtin_amdgcn_mfma_f32_16x16x32_f16(al0, bh, acc0[nt], 0, 0, 0);
                acc1[nt] = __builtin_amdgcn_mfma_f32_16x16x32_f16(ah1, bh, acc1[nt], 0, 0, 0);
                acc1[nt] = __builtin_amdgcn_mfma_f32_16x16x32_f16(ah1, bl, acc1[nt], 0, 0, 0);
                acc1[nt] = __builtin_amdgcn_mfma_f32_16x16x32_f16(al1, bh, acc1[nt], 0, 0, 0);
            }
        }
        __syncthreads();
    }

    // C/D layout: col = lane&15, row = (lane>>4)*4 + reg
    const int cb = L & 15;
    #pragma unroll
    for (int rt = 0; rt < 2; ++rt) {
        const floatx4* acc = rt ? acc1 : acc0;
        const int rb = w * 32 + rt * 16 + ((L >> 4) << 2);
        if constexpr (EPI == 0) {
            f16* Ch = (f16*)C1; f16* Cl = (f16*)C2;
            #pragma unroll
            for (int nt = 0; nt < 4; ++nt)
                #pragma unroll
                for (int r = 0; r < 4; ++r) {
                    f16 h, l; split(acc[nt][r], h, l);
                    const long o = (row0 + rb + r) * (long)Ndim + col0 + nt * 16 + cb;
                    Ch[o] = h; Cl[o] = l;
                }
        } else if constexpr (EPI == 1) {
            f16* Ch = (f16*)C1; f16* Cl = (f16*)C2;
            #pragma unroll
            for (int nt = 0; nt < 4; ++nt) {
                const int col = col0 + nt * 16 + cb;
                const float bias = e0[col];
                #pragma unroll
                for (int r = 0; r < 4; ++r) {
                    float v = acc[nt][r] + bias;
                    v = v > 0.f ? v : NEG * v;
                    f16 h, l; split(v, h, l);
                    const long o = (row0 + rb + r) * (long)Ndim + col;
                    Ch[o] = h; Cl[o] = l;
                }
            }
        } else if constexpr (EPI == 2) {
            float* C = (float*)C1;
            #pragma unroll
            for (int nt = 0; nt < 4; ++nt) {
                const int col = col0 + nt * 16 + cb;
                const float bias = e0[col];
                #pragma unroll
                for (int r = 0; r < 4; ++r)
                    C[(row0 + rb + r) * (long)Ndim + col] = acc[nt][r] + bias;
            }
        } else if constexpr (EPI == 3) {
            float* C = (float*)C1;
            const int h = blockIdx.y;
            #pragma unroll
            for (int r = 0; r < 4; ++r) {
                float s = 0.f, q = 0.f;
                #pragma unroll
                for (int nt = 0; nt < 4; ++nt) { const float v = acc[nt][r]; s += v; q += v * v; }
                s += __shfl_xor(s, 1); q += __shfl_xor(q, 1);
                s += __shfl_xor(s, 2); q += __shfl_xor(q, 2);
                s += __shfl_xor(s, 4); q += __shfl_xor(q, 4);
                s += __shfl_xor(s, 8); q += __shfl_xor(q, 8);
                const float mean = s * (1.f / 64.f);
                const float var  = q * (1.f / 64.f) - mean * mean;
                const float rs   = rsqrtf(var + LNE);
                #pragma unroll
                for (int nt = 0; nt < 4; ++nt) {
                    const int col = nt * 16 + cb;
                    C[((long)h * NT + row0 + rb + r) * 64 + col] =
                        (acc[nt][r] - mean) * rs * e0[col] + e1[col];
                }
            }
        } else {  // EPI == 5
            float* C = (float*)C1;
            #pragma unroll
            for (int nt = 0; nt < 4; ++nt)
                #pragma unroll
                for (int r = 0; r < 4; ++r) {
                    const long rr = row0 + rb + r - (long)blockIdx.y * 1536;
                    C[rr * 512 + boff + nt * 16 + cb] = acc[nt][r];
                }
        }
    }
}

// ---------------------------------------------------------------------------
// PV1: per (hb, col-tile): U[q, fd] = sum_n attn[hb][q,n] * kv[b][n, fd]
// A = attn pair [hb*64+q, 2048] row-major. B = kv pair, K-major (row n,
// stride 1536) -> transposed into LDS during staging. 3-mul split.
// Block: 64 rows x 64 cols, 4 waves x 16 rows. EPI: U pair store.
// ---------------------------------------------------------------------------
__global__ __launch_bounds__(256) void k_gemm3T(
    const f16* __restrict__ Ah, const f16* __restrict__ Al,
    const f16* __restrict__ Bh, const f16* __restrict__ Bl,
    f16* __restrict__ Uh, f16* __restrict__ Ul)
{
    __shared__ __align__(16) f16 Ash[64][72];
    __shared__ __align__(16) f16 Asl[64][72];
    __shared__ __align__(16) f16 Bsh[64][72];
    __shared__ __align__(16) f16 Bsl[64][72];

    const int t = threadIdx.x;
    const int by = blockIdx.x;
    const int hb = by / 24, ct = by % 24;
    const int b = hb & 7;
    const f16* Abh = Ah + (long)hb * 64 * 2048;
    const f16* Abl = Al + (long)hb * 64 * 2048;
    const f16* Bbh = Bh + (long)b * 2048 * 1536 + ct * 64;
    const f16* Bbl = Bl + (long)b * 2048 * 1536 + ct * 64;

    floatx4 acc[4];
    #pragma unroll
    for (int nt = 0; nt < 4; ++nt)
        #pragma unroll
        for (int j = 0; j < 4; ++j) acc[nt][j] = 0.f;

    const int L = t & 63, w = t >> 6;
    const int kq = (L >> 4) << 3;
    const int k2 = t >> 3, c8 = (t & 7) << 3;   // B-transpose mapping

    for (int k0 = 0; k0 < 2048; k0 += 64) {
        #pragma unroll
        for (int j = 0; j < 2; ++j) {
            const int i = t + j * 256;
            const int r = i >> 3, cc = (i & 7) << 3;
            *(f16x8*)&Ash[r][cc] = *(const f16x8*)&Abh[(long)r * 2048 + k0 + cc];
            *(f16x8*)&Asl[r][cc] = *(const f16x8*)&Abl[(long)r * 2048 + k0 + cc];
        }
        {
            const f16x8 r0h = *(const f16x8*)&Bbh[(long)(k0 + 2 * k2) * 1536 + c8];
            const f16x8 r1h = *(const f16x8*)&Bbh[(long)(k0 + 2 * k2 + 1) * 1536 + c8];
            const f16x8 r0l = *(const f16x8*)&Bbl[(long)(k0 + 2 * k2) * 1536 + c8];
            const f16x8 r1l = *(const f16x8*)&Bbl[(long)(k0 + 2 * k2 + 1) * 1536 + c8];
            #pragma unroll
            for (int j = 0; j < 8; ++j) {
                f16x2 ph; ph[0] = r0h[j]; ph[1] = r1h[j];
                f16x2 pl; pl[0] = r0l[j]; pl[1] = r1l[j];
                *(f16x2*)&Bsh[c8 + j][2 * k2] = ph;
                *(f16x2*)&Bsl[c8 + j][2 * k2] = pl;
            }
        }
        __syncthreads();
        #pragma unroll
        for (int kk = 0; kk < 64; kk += 32) {
            const f16x8 ah0 = *(const f16x8*)&Ash[w * 16 + (L & 15)][kk + kq];
            const f16x8 al0 = *(const f16x8*)&Asl[w * 16 + (L & 15)][kk + kq];
            #pragma unroll
            for (int nt = 0; nt < 4; ++nt) {
                const f16x8 bh = *(const f16x8*)&Bsh[nt * 16 + (L & 15)][kk + kq];
                const f16x8 bl = *(const f16x8*)&Bsl[nt * 16 + (L & 15)][kk + kq];
                acc[nt] = __builtin_amdgcn_mfma_f32_16x16x32_f16(ah0, bh, acc[nt], 0, 0, 0);
                acc[nt] = __builtin_amdgcn_mfma_f32_16x16x32_f16(ah0, bl, acc[nt], 0, 0, 0);
                acc[nt] = __builtin_amdgcn_mfma_f32_16x16x32_f16(al0, bh, acc[nt], 0, 0, 0);
            }
        }
        __syncthreads();
    }

    const int cb = L & 15;
    const int rb = w * 16 + ((L >> 4) << 2);
    #pragma unroll
    for (int nt = 0; nt < 4; ++nt)
        #pragma unroll
        for (int r = 0; r < 4; ++r) {
            f16 h, l; split(acc[nt][r], h, l);
            const long o = ((long)hb * 64 + rb + r) * 1536 + ct * 64 + nt * 16 + cb;
            Uh[o] = h; Ul[o] = l;
        }
}

// ---------------------------------------------------------------------------
// f32 [K,N] -> transposed f16 pair [N,K]
__global__ void k_castTpair(const float* __restrict__ s, f16* __restrict__ dh,
                            f16* __restrict__ dl, int K, int Nn)
{
    const long i = (long)blockIdx.x * 256 + threadIdx.x;
    if (i >= (long)K * Nn) return;
    const int k = (int)(i / Nn), n = (int)(i - (long)k * Nn);
    f16 h, l; split(s[i], h, l);
    dh[(long)n * K + k] = h;
    dl[(long)n * K + k] = l;
}

// normb pair = f16pair( sqrt(sum_f kv_pre^2) + EPS ), one thread per (tk,c)
__global__ void k_norm(const f16* __restrict__ kh, const f16* __restrict__ kl,
                       f16* __restrict__ nh, f16* __restrict__ nl)
{
    const long i = (long)blockIdx.x * 256 + threadIdx.x;
    const int tk = (int)(i >> 9), c = (int)(i & 511);
    const long base = (long)tk * 1536 + c;
    const float a = (float)kh[base]        + (float)kl[base];
    const float b = (float)kh[base + 512]  + (float)kl[base + 512];
    const float cc = (float)kh[base + 1024] + (float)kl[base + 1024];
    f16 h, l; split(sqrtf(a * a + b * b + cc * cc) + EPS, h, l);
    nh[i] = h; nl[i] = l;
}

// gate (in-place on kv pair) + kinv pair. One block per token.
__global__ __launch_bounds__(256) void k_gate(
    f16* __restrict__ kh, f16* __restrict__ kl, const float* __restrict__ g,
    f16* __restrict__ kih, f16* __restrict__ kil)
{
    __shared__ float red[3][4];
    const int t = threadIdx.x;
    const int tk = blockIdx.x;
    float kv[2][3];
    float ps0 = 0.f, ps1 = 0.f, ps2 = 0.f;
    #pragma unroll
    for (int j = 0; j < 2; ++j) {
        const int c = t + j * 256;
        const long base = (long)tk * 1536 + c;
        const float k0 = (float)kh[base]        + (float)kl[base];
        const float k1 = (float)kh[base + 512]  + (float)kl[base + 512];
        const float k2 = (float)kh[base + 1024] + (float)kl[base + 1024];
        const float nr = sqrtf(k0 * k0 + k1 * k1 + k2 * k2);
        const float gv = g[(long)tk * 512 + c];
        const float s = (nr <= EPS) ? 1.f : gv / (nr + EPS);
        kv[j][0] = k0 * s; kv[j][1] = k1 * s; kv[j][2] = k2 * s;
        f16 h, l;
        split(kv[j][0], h, l); kh[base] = h;        kl[base] = l;
        split(kv[j][1], h, l); kh[base + 512] = h;  kl[base + 512] = l;
        split(kv[j][2], h, l); kh[base + 1024] = h; kl[base + 1024] = l;
        ps0 += kv[j][0]; ps1 += kv[j][1]; ps2 += kv[j][2];
    }
    for (int off = 32; off; off >>= 1) {
        ps0 += __shfl_down(ps0, off);
        ps1 += __shfl_down(ps1, off);
        ps2 += __shfl_down(ps2, off);
    }
    if ((t & 63) == 0) { red[0][t >> 6] = ps0; red[1][t >> 6] = ps1; red[2][t >> 6] = ps2; }
    __syncthreads();
    const float m0 = (red[0][0] + red[0][1] + red[0][2] + red[0][3]) * (1.f / 512.f);
    const float m1 = (red[1][0] + red[1][1] + red[1][2] + red[1][3]) * (1.f / 512.f);
    const float m2 = (red[2][0] + red[2][1] + red[2][2] + red[2][3]) * (1.f / 512.f);
    #pragma unroll
    for (int j = 0; j < 2; ++j) {
        const int c = t + j * 256;
        f16 h, l; split(kv[j][0] * m0 + kv[j][1] * m1 + kv[j][2] * m2, h, l);
        kih[(long)tk * 512 + c] = h;
        kil[(long)tk * 512 + c] = l;
    }
}

// ---------------------------------------------------------------------------
// q = LN(lq @ wq) per head (fp32 VALU, tiny). One block per qi.
__global__ __launch_bounds__(256) void k_qproj(
    const float* __restrict__ lq, const float* __restrict__ wq,
    const float* __restrict__ lns, const float* __restrict__ lnb,
    float* __restrict__ qout)
{
    __shared__ float cs[QK];
    const int t = threadIdx.x;
    const int qi = blockIdx.x;
    const float* cp = lq + (long)qi * QK;
    for (int i = t; i < QK; i += 256) cs[i] = cp[i];
    __syncthreads();

    float a0 = 0, a1 = 0;
    #pragma unroll 4
    for (int d = 0; d < QK; ++d) {
        const float c = cs[d];
        a0 += c * wq[d * QK + t];
        a1 += c * wq[d * QK + t + 256];
    }
    float s0 = a0, q0 = a0 * a0, s1 = a1, q1 = a1 * a1;
    for (int off = 32; off; off >>= 1) {
        s0 += __shfl_down(s0, off); q0 += __shfl_down(q0, off);
        s1 += __shfl_down(s1, off); q1 += __shfl_down(q1, off);
    }
    s0 = __shfl(s0, 0); q0 = __shfl(q0, 0);
    s1 = __shfl(s1, 0); q1 = __shfl(q1, 0);
    const float mean0 = s0 * (1.f / 64.f), var0 = q0 * (1.f / 64.f) - mean0 * mean0;
    const float mean1 = s1 * (1.f / 64.f), var1 = q1 * (1.f / 64.f) - mean1 * mean1;
    const int e = t & 63;
    const float sc = lns[e], bi = lnb[e];
    const float r0 = (a0 - mean0) * rsqrtf(var0 + LNE) * sc + bi;
    const float r1 = (a1 - mean1) * rsqrtf(var1 + LNE) * sc + bi;
    const int h0 = t >> 6, h1 = h0 + 4;
    qout[((long)h0 * Qq + qi) * DH + e] = r0;
    qout[((long)h1 * Qq + qi) * DH + e] = r1;
}

// ---------------------------------------------------------------------------
// attn = softmax over n of (q.k)/8, stored as f16 pair. One block per (hb,qi).
__global__ __launch_bounds__(256) void k_attn(
    const float* __restrict__ qv, const float* __restrict__ kf,
    f16* __restrict__ ah, f16* __restrict__ al)
{
    __shared__ float qs[DH];
    __shared__ float ks[128 * 65];
    __shared__ float sc[N];
    __shared__ float red[4];

    const int t = threadIdx.x;
    const int idx = blockIdx.x;
    const int qi = idx & (Qq - 1);
    const int hb = idx / Qq;
    if (t < DH) qs[t] = qv[((long)(hb / B) * Qq + qi) * DH + t];
    const float* kp = kf + (long)hb * N * DH;

    for (int T = 0; T < N / 128; ++T) {
        __syncthreads();
        for (int i = t; i < 128 * DH; i += 256) {
            int n = i >> 6, e = i & 63;
            ks[n * 65 + e] = kp[(long)T * 128 * DH + i];
        }
        __syncthreads();
        if (t < 128) {
            float s = 0;
            #pragma unroll 8
            for (int e = 0; e < DH; ++e) s += qs[e] * ks[t * 65 + e];
            sc[T * 128 + t] = s * 0.125f;
        }
    }
    __syncthreads();

    float lm = -1e30f;
    for (int i = t; i < N; i += 256) lm = fmaxf(lm, sc[i]);
    for (int off = 32; off; off >>= 1) lm = fmaxf(lm, __shfl_down(lm, off));
    if ((t & 63) == 0) red[t >> 6] = lm;
    __syncthreads();
    const float m = fmaxf(fmaxf(red[0], red[1]), fmaxf(red[2], red[3]));
    __syncthreads();
    float ls = 0;
    for (int i = t; i < N; i += 256) {
        const float p = __expf(sc[i] - m);
        sc[i] = p;
        ls += p;
    }
    for (int off = 32; off; off >>= 1) ls += __shfl_down(ls, off);
    if ((t & 63) == 0) red[t >> 6] = ls;
    __syncthreads();
    const float inv = 1.f / (red[0] + red[1] + red[2] + red[3]);
    for (int i = t; i < N; i += 256) {
        f16 h, l; split(sc[i] * inv, h, l);
        ah[(long)idx * N + i] = h;
        al[(long)idx * N + i] = l;
    }
}

// ---------------------------------------------------------------------------
// out = EVN2(resiT @ w_out), fp32 store. One block per (b,q).
__global__ __launch_bounds__(256) void k_out(
    const float* __restrict__ resiT, const float* __restrict__ w_out,
    const float* __restrict__ w2a, const float* __restrict__ b2a,
    const float* __restrict__ w2b, const float* __restrict__ b2b,
    float* __restrict__ out)
{
    __shared__ float rs[Fv * Vd];
    __shared__ float norm_s[Vd];
    __shared__ float h_s[256];

    const int t = threadIdx.x;
    const long bq = blockIdx.x;
    const float* rp = resiT + bq * (Fv * Vd);
    for (int i = t; i < Fv * Vd; i += 256) rs[i] = rp[i];
    __syncthreads();

    float a0 = 0, a1 = 0, a2 = 0, a3 = 0, a4 = 0, a5 = 0;
    #pragma unroll 4
    for (int d = 0; d < Vd; ++d) {
        const float w0 = w_out[d * Vd + t];
        const float w1 = w_out[d * Vd + t + 256];
        const float x0 = rs[d], x1 = rs[Vd + d], x2 = rs[2 * Vd + d];
        a0 += x0 * w0; a1 += x1 * w0; a2 += x2 * w0;
        a3 += x0 * w1; a4 += x1 * w1; a5 += x2 * w1;
    }
    const float nrm0 = sqrtf(a0 * a0 + a1 * a1 + a2 * a2);
    const float nrm1 = sqrtf(a3 * a3 + a4 * a4 + a5 * a5);
    norm_s[t] = nrm0;
    norm_s[t + 256] = nrm1;
    __syncthreads();

    float hacc = b2a[t];
    #pragma unroll 4
    for (int d = 0; d < Vd; ++d) hacc += (norm_s[d] + EPS) * w2a[d * 256 + t];
    h_s[t] = hacc > 0.f ? hacc : NEG * hacc;
    __syncthreads();

    float g0 = b2b[t], g1 = b2b[t + 256];
    #pragma unroll 4
    for (int j = 0; j < 256; ++j) {
        const float hv = h_s[j];
        g0 += hv * w2b[j * Vd + t];
        g1 += hv * w2b[j * Vd + t + 256];
    }
    const float s0 = (nrm0 <= EPS) ? 1.f : g0 / (nrm0 + EPS);
    const float s1 = (nrm1 <= EPS) ? 1.f : g1 / (nrm1 + EPS);

    float* op = out + bq * (Fv * Vd);
    op[0 * Vd + t]       = a0 * s0;
    op[1 * Vd + t]       = a1 * s0;
    op[2 * Vd + t]       = a2 * s0;
    op[0 * Vd + t + 256] = a3 * s1;
    op[1 * Vd + t + 256] = a4 * s1;
    op[2 * Vd + t + 256] = a5 * s1;
}

// ---------------------------------------------------------------------------
extern "C" void kernel_launch(void* const* d_in, const int* in_sizes, int n_in,
                              void* d_out, int out_size, void* d_ws, size_t ws_size,
                              hipStream_t stream)
{
    const float* x    = (const float*)d_in[0];
    const float* lq   = (const float*)d_in[1];
    const float* w_kv = (const float*)d_in[2];
    const float* w1a  = (const float*)d_in[3];
    const float* b1a  = (const float*)d_in[4];
    const float* w1b  = (const float*)d_in[5];
    const float* b1b  = (const float*)d_in[6];
    const float* wq   = (const float*)d_in[7];
    const float* wk   = (const float*)d_in[8];
    const float* wv   = (const float*)d_in[9];
    const float* lqs  = (const float*)d_in[10];
    const float* lqb  = (const float*)d_in[11];
    const float* lks  = (const float*)d_in[12];
    const float* lkb  = (const float*)d_in[13];
    const float* wo   = (const float*)d_in[14];
    const float* w2a  = (const float*)d_in[15];
    const float* b2a  = (const float*)d_in[16];
    const float* w2b  = (const float*)d_in[17];
    const float* b2b  = (const float*)d_in[18];

    char* ws = (char*)d_ws;
    // Layout (191.5 MB, lifetime-aliased):
    //  W [0, 3.67M): weight pairs
    //  S [3.67M, 6.95M): qbuf, resiT
    //  A1 [6.95M, 40.5M): normb pair -> kinv pair -> attn pair
    //  A2 [40.5M, 57.3M): hb pair
    //  B  [57.3M, 157.9M): kv pair (pre -> gated in-place)
    //  D  [157.9M, 191.5M): g f32 -> kbuf f32 -> U pair
    f16* wkvTh = (f16*)(ws + 0);
    f16* wkvTl = (f16*)(ws + 262144);
    f16* w1aTh = (f16*)(ws + 524288);
    f16* w1aTl = (f16*)(ws + 786432);
    f16* w1bTh = (f16*)(ws + 1048576);
    f16* w1bTl = (f16*)(ws + 1310720);
    f16* wkTh  = (f16*)(ws + 1572864);
    f16* wkTl  = (f16*)(ws + 2097152);
    f16* wvTh  = (f16*)(ws + 2621440);
    f16* wvTl  = (f16*)(ws + 3145728);
    float* qbuf  = (float*)(ws + 3670016);
    float* resiT = (float*)(ws + 3801088);
    f16* nh    = (f16*)(ws + 6946816);
    f16* nl    = (f16*)(ws + 23724032);
    f16* kih   = nh;
    f16* kil   = nl;
    f16* ath   = nh;
    f16* atl   = nl;
    f16* hbh   = (f16*)(ws + 40501248);
    f16* hbl   = (f16*)(ws + 48889856);
    f16* kvh   = (f16*)(ws + 57278464);
    f16* kvl   = (f16*)(ws + 107610112);
    float* g    = (float*)(ws + 157941760);
    float* kbuf = (float*)(ws + 157941760);
    f16* Uh    = (f16*)(ws + 157941760);
    f16* Ul    = (f16*)(ws + 170524672);
    float* out  = (float*)d_out;

    // 1. weight casts (transposed pairs)
    k_castTpair<<<512,  256, 0, stream>>>(w_kv, wkvTh, wkvTl, Dd, QK);
    k_castTpair<<<512,  256, 0, stream>>>(w1a,  w1aTh, w1aTl, QK, 256);
    k_castTpair<<<512,  256, 0, stream>>>(w1b,  w1bTh, w1bTl, 256, QK);
    k_castTpair<<<1024, 256, 0, stream>>>(wk,   wkTh,  wkTl,  QK, QK);
    k_castTpair<<<1024, 256, 0, stream>>>(wv,   wvTh,  wvTl,  QK, QK);

    // 2. kv_pre = x @ w_kv   (A = fp32 x, split on the fly) -> kv pair
    k_gemm3<1, 0><<<dim3(384, 8), 256, 0, stream>>>(
        x, nullptr, nullptr, wkvTh, wkvTl, QK, Dd, kvh, kvl, nullptr, nullptr);
    // 3. norm
    k_norm<<<32768, 256, 0, stream>>>(kvh, kvl, nh, nl);
    // 4. h = leaky(norm @ w1a + b1a) -> hb pair
    k_gemm3<0, 1><<<dim3(128, 4), 256, 0, stream>>>(
        nullptr, nh, nl, w1aTh, w1aTl, 256, QK, hbh, hbl, b1a, nullptr);
    // 5. g = h @ w1b + b1b -> f32
    k_gemm3<0, 2><<<dim3(128, 8), 256, 0, stream>>>(
        nullptr, hbh, hbl, w1bTh, w1bTl, QK, 256, g, nullptr, b1b, nullptr);
    // 6. gate in-place + kinv pair
    k_gate<<<NT, 256, 0, stream>>>(kvh, kvl, g, kih, kil);
    // 7. k = LN(kinv @ wk) -> kbuf f32 [h][tok][64]
    k_gemm3<0, 3><<<dim3(128, 8), 256, 0, stream>>>(
        nullptr, kih, kil, wkTh, wkTl, QK, QK, kbuf, nullptr, lks, lkb);
    // 8. q
    k_qproj<<<Qq, 256, 0, stream>>>(lq, wq, lqs, lqb, qbuf);
    // 9. attn -> pair
    k_attn<<<Hh * B * Qq, 256, 0, stream>>>(qbuf, kbuf, ath, atl);
    // 10. U = attn @ kv  -> U pair
    k_gemm3T<<<64 * 24, 256, 0, stream>>>(ath, atl, kvh, kvl, Uh, Ul);
    // 11. resi = U @ wv -> resiT f32
    k_gemm3<0, 5><<<dim3(12, 8), 256, 0, stream>>>(
        nullptr, Uh, Ul, wvTh, wvTl, 64, QK, resiT, nullptr, nullptr, nullptr);
    // 12. out
    k_out<<<B * Qq, 256, 0, stream>>>(resiT, wo, w2a, b2a, w2b, b2b, out);
}

// Round 8
// 833.818 us; speedup vs baseline: 2.2030x; 1.1205x over previous
//
#include <hip/hip_runtime.h>
#include <hip/hip_bf16.h>

typedef _Float16 f16;
typedef __attribute__((ext_vector_type(8))) _Float16 f16x8;
typedef __attribute__((ext_vector_type(4))) _Float16 f16x4;
typedef __attribute__((ext_vector_type(2))) _Float16 f16x2;
typedef __attribute__((ext_vector_type(4))) float floatx4;

// Problem constants
constexpr int B  = 8;
constexpr int N  = 2048;
constexpr int Fv = 3;
constexpr int Dd = 256;
constexpr int QK = 512;
constexpr int Vd = 512;
constexpr int Hh = 8;
constexpr int Qq = 64;
constexpr int DH = 64;
constexpr int NT = B * N;          // 16384 tokens
constexpr float EPS = 1e-6f;
constexpr float NEG = 0.2f;
constexpr float LNE = 1e-6f;

#define DEV static __device__ __forceinline__
DEV void split(float v, f16& h, f16& l) { h = (f16)v; l = (f16)(v - (float)h); }

// ---------------------------------------------------------------------------
// Split-fp16 3-mul GEMM (effective fp32 accuracy): C = A[M,K] @ B[K,N]
// A as (Ah,Al) f16 pairs (ASRC=0) or fp32 split on the fly (ASRC=1).
// Bt = B^T row-major [N,K] as (Bh,Bl) pairs.
// Block 256 thr = 4 waves; tile 128M x 64N; wave = 32 rows x 64 cols.
// EPI: 0 pair store (kv_pre)        1 +bias,leaky -> pair (hb)
//      2 +bias -> f32 (g)           3 per-64col LN -> f16 pair [h][tok][64]
//      5 PV2: store f32 resiT[(b,q,f)][512] at col h*64+
// ---------------------------------------------------------------------------
template<int ASRC, int EPI>
__global__ __launch_bounds__(256) void k_gemm3(
    const float* __restrict__ A32,
    const f16* __restrict__ Ah, const f16* __restrict__ Al,
    const f16* __restrict__ Bh, const f16* __restrict__ Bl,
    int Ndim, int Kdim, void* __restrict__ C1, void* __restrict__ C2,
    const float* __restrict__ e0, const float* __restrict__ e1)
{
    __shared__ __align__(16) f16 Ash[128][72];
    __shared__ __align__(16) f16 Asl[128][72];
    __shared__ __align__(16) f16 Bsh[64][72];
    __shared__ __align__(16) f16 Bsl[64][72];

    const int t = threadIdx.x;
    long row0; int col0, boff;
    if (EPI == 5) { row0 = (long)blockIdx.y * 1536 + (long)blockIdx.x * 128; col0 = 0; boff = blockIdx.y * 64; }
    else          { row0 = (long)blockIdx.x * 128; col0 = blockIdx.y * 64; boff = 0; }

    floatx4 acc0[4], acc1[4];
    #pragma unroll
    for (int nt = 0; nt < 4; ++nt)
        #pragma unroll
        for (int j = 0; j < 4; ++j) { acc0[nt][j] = 0.f; acc1[nt][j] = 0.f; }

    const int L = t & 63, w = t >> 6;
    const int kq = (L >> 4) << 3;

    for (int k0 = 0; k0 < Kdim; k0 += 64) {
        if constexpr (ASRC == 1) {
            #pragma unroll
            for (int j = 0; j < 8; ++j) {
                const int i = t + j * 256;
                const int r = i >> 4, c4 = (i & 15) << 2;
                const floatx4 v = *(const floatx4*)&A32[(row0 + r) * Kdim + k0 + c4];
                f16x4 h4, l4;
                #pragma unroll
                for (int m = 0; m < 4; ++m) { h4[m] = (f16)v[m]; l4[m] = (f16)(v[m] - (float)h4[m]); }
                *(f16x4*)&Ash[r][c4] = h4;
                *(f16x4*)&Asl[r][c4] = l4;
            }
        } else {
            #pragma unroll
            for (int j = 0; j < 4; ++j) {
                const int i = t + j * 256;
                const int r = i >> 3, c8 = (i & 7) << 3;
                *(f16x8*)&Ash[r][c8] = *(const f16x8*)&Ah[(row0 + r) * (long)Kdim + k0 + c8];
                *(f16x8*)&Asl[r][c8] = *(const f16x8*)&Al[(row0 + r) * (long)Kdim + k0 + c8];
            }
        }
        #pragma unroll
        for (int j = 0; j < 2; ++j) {
            const int i = t + j * 256;
            const int r = i >> 3, c8 = (i & 7) << 3;
            *(f16x8*)&Bsh[r][c8] = *(const f16x8*)&Bh[(long)(boff + col0 + r) * Kdim + k0 + c8];
            *(f16x8*)&Bsl[r][c8] = *(const f16x8*)&Bl[(long)(boff + col0 + r) * Kdim + k0 + c8];
        }
        __syncthreads();
        #pragma unroll
        for (int kk = 0; kk < 64; kk += 32) {
            const f16x8 ah0 = *(const f16x8*)&Ash[w * 32 + (L & 15)][kk + kq];
            const f16x8 al0 = *(const f16x8*)&Asl[w * 32 + (L & 15)][kk + kq];
            const f16x8 ah1 = *(const f16x8*)&Ash[w * 32 + 16 + (L & 15)][kk + kq];
            const f16x8 al1 = *(const f16x8*)&Asl[w * 32 + 16 + (L & 15)][kk + kq];
            #pragma unroll
            for (int nt = 0; nt < 4; ++nt) {
                const f16x8 bh = *(const f16x8*)&Bsh[nt * 16 + (L & 15)][kk + kq];
                const f16x8 bl = *(const f16x8*)&Bsl[nt * 16 + (L & 15)][kk + kq];
                acc0[nt] = __builtin_amdgcn_mfma_f32_16x16x32_f16(ah0, bh, acc0[nt], 0, 0, 0);
                acc0[nt] = __builtin_amdgcn_mfma_f32_16x16x32_f16(ah0, bl, acc0[nt], 0, 0, 0);
                acc0[nt] = __builtin_amdgcn_mfma_f32_16x16x32_f16(al0, bh, acc0[nt], 0, 0, 0);
                acc1[nt] = __builtin_amdgcn_mfma_f32_16x16x32_f16(ah1, bh, acc1[nt], 0, 0, 0);
                acc1[nt] = __builtin_amdgcn_mfma_f32_16x16x32_f16(ah1, bl, acc1[nt], 0, 0, 0);
                acc1[nt] = __builtin_amdgcn_mfma_f32_16x16x32_f16(al1, bh, acc1[nt], 0, 0, 0);
            }
        }
        __syncthreads();
    }

    // C/D layout: col = lane&15, row = (lane>>4)*4 + reg
    const int cb = L & 15;
    #pragma unroll
    for (int rt = 0; rt < 2; ++rt) {
        const floatx4* acc = rt ? acc1 : acc0;
        const int rb = w * 32 + rt * 16 + ((L >> 4) << 2);
        if constexpr (EPI == 0) {
            f16* Ch = (f16*)C1; f16* Cl = (f16*)C2;
            #pragma unroll
            for (int nt = 0; nt < 4; ++nt)
                #pragma unroll
                for (int r = 0; r < 4; ++r) {
                    f16 h, l; split(acc[nt][r], h, l);
                    const long o = (row0 + rb + r) * (long)Ndim + col0 + nt * 16 + cb;
                    Ch[o] = h; Cl[o] = l;
                }
        } else if constexpr (EPI == 1) {
            f16* Ch = (f16*)C1; f16* Cl = (f16*)C2;
            #pragma unroll
            for (int nt = 0; nt < 4; ++nt) {
                const int col = col0 + nt * 16 + cb;
                const float bias = e0[col];
                #pragma unroll
                for (int r = 0; r < 4; ++r) {
                    float v = acc[nt][r] + bias;
                    v = v > 0.f ? v : NEG * v;
                    f16 h, l; split(v, h, l);
                    const long o = (row0 + rb + r) * (long)Ndim + col;
                    Ch[o] = h; Cl[o] = l;
                }
            }
        } else if constexpr (EPI == 2) {
            float* C = (float*)C1;
            #pragma unroll
            for (int nt = 0; nt < 4; ++nt) {
                const int col = col0 + nt * 16 + cb;
                const float bias = e0[col];
                #pragma unroll
                for (int r = 0; r < 4; ++r)
                    C[(row0 + rb + r) * (long)Ndim + col] = acc[nt][r] + bias;
            }
        } else if constexpr (EPI == 3) {
            f16* Ch = (f16*)C1; f16* Cl = (f16*)C2;
            const int h = blockIdx.y;
            #pragma unroll
            for (int r = 0; r < 4; ++r) {
                float s = 0.f, q = 0.f;
                #pragma unroll
                for (int nt = 0; nt < 4; ++nt) { const float v = acc[nt][r]; s += v; q += v * v; }
                s += __shfl_xor(s, 1); q += __shfl_xor(q, 1);
                s += __shfl_xor(s, 2); q += __shfl_xor(q, 2);
                s += __shfl_xor(s, 4); q += __shfl_xor(q, 4);
                s += __shfl_xor(s, 8); q += __shfl_xor(q, 8);
                const float mean = s * (1.f / 64.f);
                const float var  = q * (1.f / 64.f) - mean * mean;
                const float rs   = rsqrtf(var + LNE);
                #pragma unroll
                for (int nt = 0; nt < 4; ++nt) {
                    const int col = nt * 16 + cb;
                    const float v = (acc[nt][r] - mean) * rs * e0[col] + e1[col];
                    f16 hh, ll; split(v, hh, ll);
                    const long o = ((long)h * NT + row0 + rb + r) * 64 + col;
                    Ch[o] = hh; Cl[o] = ll;
                }
            }
        } else {  // EPI == 5
            float* C = (float*)C1;
            #pragma unroll
            for (int nt = 0; nt < 4; ++nt)
                #pragma unroll
                for (int r = 0; r < 4; ++r) {
                    const long rr = row0 + rb + r - (long)blockIdx.y * 1536;
                    C[rr * 512 + boff + nt * 16 + cb] = acc[nt][r];
                }
        }
    }
}

// ---------------------------------------------------------------------------
// Attention scores via MFMA, one block per hb = h*B+b.
// S[q,n] = (qv . k)/8 ; p = exp(S) (no max-sub: |S|<=8 after LN);
// store p (f32, unnormalized) + row sums lsum. Normalization folded into PV.
// ---------------------------------------------------------------------------
__global__ __launch_bounds__(256) void k_attn_mfma(
    const f16* __restrict__ qh, const f16* __restrict__ ql,
    const f16* __restrict__ kh, const f16* __restrict__ kl,
    float* __restrict__ attn, float* __restrict__ lsum)
{
    __shared__ __align__(16) f16 Qh[64][72], Ql[64][72];
    __shared__ __align__(16) f16 Kh[64][72], Kl[64][72];

    const int t = threadIdx.x;
    const int hb = blockIdx.x;
    const int h = hb >> 3;
    const int L = t & 63, w = t >> 6;
    const int kq = (L >> 4) << 3;

    // stage Q (64 q-rows x 64 e)
    #pragma unroll
    for (int j = 0; j < 2; ++j) {
        const int i = t + j * 256;
        const int r = i >> 3, c8 = (i & 7) << 3;
        *(f16x8*)&Qh[r][c8] = *(const f16x8*)&qh[((long)h * 64 + r) * 64 + c8];
        *(f16x8*)&Ql[r][c8] = *(const f16x8*)&ql[((long)h * 64 + r) * 64 + c8];
    }
    __syncthreads();

    // persistent A-frags: wave w owns q-rows w*16..w*16+15
    f16x8 qah[2], qal[2];
    #pragma unroll
    for (int kc = 0; kc < 2; ++kc) {
        qah[kc] = *(const f16x8*)&Qh[w * 16 + (L & 15)][kc * 32 + kq];
        qal[kc] = *(const f16x8*)&Ql[w * 16 + (L & 15)][kc * 32 + kq];
    }

    float psum[4] = {0.f, 0.f, 0.f, 0.f};
    const int rowb = w * 16 + ((L >> 4) << 2);

    for (int n0 = 0; n0 < N; n0 += 64) {
        __syncthreads();
        #pragma unroll
        for (int j = 0; j < 2; ++j) {
            const int i = t + j * 256;
            const int r = i >> 3, c8 = (i & 7) << 3;
            *(f16x8*)&Kh[r][c8] = *(const f16x8*)&kh[((long)hb * N + n0 + r) * 64 + c8];
            *(f16x8*)&Kl[r][c8] = *(const f16x8*)&kl[((long)hb * N + n0 + r) * 64 + c8];
        }
        __syncthreads();

        floatx4 acc[4];
        #pragma unroll
        for (int nt = 0; nt < 4; ++nt)
            #pragma unroll
            for (int j = 0; j < 4; ++j) acc[nt][j] = 0.f;

        #pragma unroll
        for (int kc = 0; kc < 2; ++kc) {
            #pragma unroll
            for (int nt = 0; nt < 4; ++nt) {
                const f16x8 bh = *(const f16x8*)&Kh[nt * 16 + (L & 15)][kc * 32 + kq];
                const f16x8 bl = *(const f16x8*)&Kl[nt * 16 + (L & 15)][kc * 32 + kq];
                acc[nt] = __builtin_amdgcn_mfma_f32_16x16x32_f16(qah[kc], bh, acc[nt], 0, 0, 0);
                acc[nt] = __builtin_amdgcn_mfma_f32_16x16x32_f16(qah[kc], bl, acc[nt], 0, 0, 0);
                acc[nt] = __builtin_amdgcn_mfma_f32_16x16x32_f16(qal[kc], bh, acc[nt], 0, 0, 0);
            }
        }

        #pragma unroll
        for (int nt = 0; nt < 4; ++nt)
            #pragma unroll
            for (int r = 0; r < 4; ++r) {
                const float p = __expf(acc[nt][r] * 0.125f);
                psum[r] += p;
                attn[((long)hb * 64 + rowb + r) * N + n0 + nt * 16 + (L & 15)] = p;
            }
    }

    // reduce row sums across the 16 lanes sharing each row
    #pragma unroll
    for (int r = 0; r < 4; ++r) {
        float s = psum[r];
        s += __shfl_xor(s, 1);
        s += __shfl_xor(s, 2);
        s += __shfl_xor(s, 4);
        s += __shfl_xor(s, 8);
        if ((L & 15) == 0) lsum[hb * 64 + rowb + r] = s;
    }
}

// ---------------------------------------------------------------------------
// PV1: U[hb*64+q, fd] = (1/lsum[row]) * sum_n p[row,n] * kv[b][n, fd]
// A = unnormalized attn f32 (split on the fly); B = kv pair, K-major
// (row n, stride 1536) transposed into LDS. Output U pair.
// ---------------------------------------------------------------------------
__global__ __launch_bounds__(256) void k_gemm3T(
    const float* __restrict__ A32,
    const f16* __restrict__ Bh, const f16* __restrict__ Bl,
    const float* __restrict__ lsum,
    f16* __restrict__ Uh, f16* __restrict__ Ul)
{
    __shared__ __align__(16) f16 Ash[64][72];
    __shared__ __align__(16) f16 Asl[64][72];
    __shared__ __align__(16) f16 Bsh[64][72];
    __shared__ __align__(16) f16 Bsl[64][72];

    const int t = threadIdx.x;
    const int by = blockIdx.x;
    const int hb = by / 24, ct = by % 24;
    const int b = hb & 7;
    const float* Ab = A32 + (long)hb * 64 * 2048;
    const f16* Bbh = Bh + (long)b * 2048 * 1536 + ct * 64;
    const f16* Bbl = Bl + (long)b * 2048 * 1536 + ct * 64;

    floatx4 acc[4];
    #pragma unroll
    for (int nt = 0; nt < 4; ++nt)
        #pragma unroll
        for (int j = 0; j < 4; ++j) acc[nt][j] = 0.f;

    const int L = t & 63, w = t >> 6;
    const int kq = (L >> 4) << 3;
    const int k2 = t >> 3, c8 = (t & 7) << 3;   // B-transpose mapping

    for (int k0 = 0; k0 < 2048; k0 += 64) {
        #pragma unroll
        for (int j = 0; j < 4; ++j) {
            const int i = t + j * 256;
            const int r = i >> 4, c4 = (i & 15) << 2;
            const floatx4 v = *(const floatx4*)&Ab[(long)r * 2048 + k0 + c4];
            f16x4 h4, l4;
            #pragma unroll
            for (int m = 0; m < 4; ++m) { h4[m] = (f16)v[m]; l4[m] = (f16)(v[m] - (float)h4[m]); }
            *(f16x4*)&Ash[r][c4] = h4;
            *(f16x4*)&Asl[r][c4] = l4;
        }
        {
            const f16x8 r0h = *(const f16x8*)&Bbh[(long)(k0 + 2 * k2) * 1536 + c8];
            const f16x8 r1h = *(const f16x8*)&Bbh[(long)(k0 + 2 * k2 + 1) * 1536 + c8];
            const f16x8 r0l = *(const f16x8*)&Bbl[(long)(k0 + 2 * k2) * 1536 + c8];
            const f16x8 r1l = *(const f16x8*)&Bbl[(long)(k0 + 2 * k2 + 1) * 1536 + c8];
            #pragma unroll
            for (int j = 0; j < 8; ++j) {
                f16x2 ph; ph[0] = r0h[j]; ph[1] = r1h[j];
                f16x2 pl; pl[0] = r0l[j]; pl[1] = r1l[j];
                *(f16x2*)&Bsh[c8 + j][2 * k2] = ph;
                *(f16x2*)&Bsl[c8 + j][2 * k2] = pl;
            }
        }
        __syncthreads();
        #pragma unroll
        for (int kk = 0; kk < 64; kk += 32) {
            const f16x8 ah0 = *(const f16x8*)&Ash[w * 16 + (L & 15)][kk + kq];
            const f16x8 al0 = *(const f16x8*)&Asl[w * 16 + (L & 15)][kk + kq];
            #pragma unroll
            for (int nt = 0; nt < 4; ++nt) {
                const f16x8 bh = *(const f16x8*)&Bsh[nt * 16 + (L & 15)][kk + kq];
                const f16x8 bl = *(const f16x8*)&Bsl[nt * 16 + (L & 15)][kk + kq];
                acc[nt] = __builtin_amdgcn_mfma_f32_16x16x32_f16(ah0, bh, acc[nt], 0, 0, 0);
                acc[nt] = __builtin_amdgcn_mfma_f32_16x16x32_f16(ah0, bl, acc[nt], 0, 0, 0);
                acc[nt] = __builtin_amdgcn_mfma_f32_16x16x32_f16(al0, bh, acc[nt], 0, 0, 0);
            }
        }
        __syncthreads();
    }

    const int cb = L & 15;
    const int rb = w * 16 + ((L >> 4) << 2);
    #pragma unroll
    for (int r = 0; r < 4; ++r) {
        const float inv = 1.f / lsum[hb * 64 + rb + r];
        #pragma unroll
        for (int nt = 0; nt < 4; ++nt) {
            f16 h, l; split(acc[nt][r] * inv, h, l);
            const long o = ((long)hb * 64 + rb + r) * 1536 + ct * 64 + nt * 16 + cb;
            Uh[o] = h; Ul[o] = l;
        }
    }
}

// ---------------------------------------------------------------------------
// f32 [K,N] -> transposed f16 pair [N,K]
__global__ void k_castTpair(const float* __restrict__ s, f16* __restrict__ dh,
                            f16* __restrict__ dl, int K, int Nn)
{
    const long i = (long)blockIdx.x * 256 + threadIdx.x;
    if (i >= (long)K * Nn) return;
    const int k = (int)(i / Nn), n = (int)(i - (long)k * Nn);
    f16 h, l; split(s[i], h, l);
    dh[(long)n * K + k] = h;
    dl[(long)n * K + k] = l;
}

// normb pair = f16pair( sqrt(sum_f kv_pre^2) + EPS ), one thread per (tk,c)
__global__ void k_norm(const f16* __restrict__ kh, const f16* __restrict__ kl,
                       f16* __restrict__ nh, f16* __restrict__ nl)
{
    const long i = (long)blockIdx.x * 256 + threadIdx.x;
    const int tk = (int)(i >> 9), c = (int)(i & 511);
    const long base = (long)tk * 1536 + c;
    const float a = (float)kh[base]        + (float)kl[base];
    const float b = (float)kh[base + 512]  + (float)kl[base + 512];
    const float cc = (float)kh[base + 1024] + (float)kl[base + 1024];
    f16 h, l; split(sqrtf(a * a + b * b + cc * cc) + EPS, h, l);
    nh[i] = h; nl[i] = l;
}

// gate (in-place on kv pair) + kinv pair. One block per token.
__global__ __launch_bounds__(256) void k_gate(
    f16* __restrict__ kh, f16* __restrict__ kl, const float* __restrict__ g,
    f16* __restrict__ kih, f16* __restrict__ kil)
{
    __shared__ float red[3][4];
    const int t = threadIdx.x;
    const int tk = blockIdx.x;
    float kv[2][3];
    float ps0 = 0.f, ps1 = 0.f, ps2 = 0.f;
    #pragma unroll
    for (int j = 0; j < 2; ++j) {
        const int c = t + j * 256;
        const long base = (long)tk * 1536 + c;
        const float k0 = (float)kh[base]        + (float)kl[base];
        const float k1 = (float)kh[base + 512]  + (float)kl[base + 512];
        const float k2 = (float)kh[base + 1024] + (float)kl[base + 1024];
        const float nr = sqrtf(k0 * k0 + k1 * k1 + k2 * k2);
        const float gv = g[(long)tk * 512 + c];
        const float s = (nr <= EPS) ? 1.f : gv / (nr + EPS);
        kv[j][0] = k0 * s; kv[j][1] = k1 * s; kv[j][2] = k2 * s;
        f16 h, l;
        split(kv[j][0], h, l); kh[base] = h;        kl[base] = l;
        split(kv[j][1], h, l); kh[base + 512] = h;  kl[base + 512] = l;
        split(kv[j][2], h, l); kh[base + 1024] = h; kl[base + 1024] = l;
        ps0 += kv[j][0]; ps1 += kv[j][1]; ps2 += kv[j][2];
    }
    for (int off = 32; off; off >>= 1) {
        ps0 += __shfl_down(ps0, off);
        ps1 += __shfl_down(ps1, off);
        ps2 += __shfl_down(ps2, off);
    }
    if ((t & 63) == 0) { red[0][t >> 6] = ps0; red[1][t >> 6] = ps1; red[2][t >> 6] = ps2; }
    __syncthreads();
    const float m0 = (red[0][0] + red[0][1] + red[0][2] + red[0][3]) * (1.f / 512.f);
    const float m1 = (red[1][0] + red[1][1] + red[1][2] + red[1][3]) * (1.f / 512.f);
    const float m2 = (red[2][0] + red[2][1] + red[2][2] + red[2][3]) * (1.f / 512.f);
    #pragma unroll
    for (int j = 0; j < 2; ++j) {
        const int c = t + j * 256;
        f16 h, l; split(kv[j][0] * m0 + kv[j][1] * m1 + kv[j][2] * m2, h, l);
        kih[(long)tk * 512 + c] = h;
        kil[(long)tk * 512 + c] = l;
    }
}

// ---------------------------------------------------------------------------
// q = LN(lq @ wq) per head (fp32 VALU, tiny), output f16 pair [h][qi][64].
__global__ __launch_bounds__(256) void k_qproj(
    const float* __restrict__ lq, const float* __restrict__ wq,
    const float* __restrict__ lns, const float* __restrict__ lnb,
    f16* __restrict__ qh, f16* __restrict__ ql)
{
    __shared__ float cs[QK];
    const int t = threadIdx.x;
    const int qi = blockIdx.x;
    const float* cp = lq + (long)qi * QK;
    for (int i = t; i < QK; i += 256) cs[i] = cp[i];
    __syncthreads();

    float a0 = 0, a1 = 0;
    #pragma unroll 4
    for (int d = 0; d < QK; ++d) {
        const float c = cs[d];
        a0 += c * wq[d * QK + t];
        a1 += c * wq[d * QK + t + 256];
    }
    float s0 = a0, q0 = a0 * a0, s1 = a1, q1 = a1 * a1;
    for (int off = 32; off; off >>= 1) {
        s0 += __shfl_down(s0, off); q0 += __shfl_down(q0, off);
        s1 += __shfl_down(s1, off); q1 += __shfl_down(q1, off);
    }
    s0 = __shfl(s0, 0); q0 = __shfl(q0, 0);
    s1 = __shfl(s1, 0); q1 = __shfl(q1, 0);
    const float mean0 = s0 * (1.f / 64.f), var0 = q0 * (1.f / 64.f) - mean0 * mean0;
    const float mean1 = s1 * (1.f / 64.f), var1 = q1 * (1.f / 64.f) - mean1 * mean1;
    const int e = t & 63;
    const float sc = lns[e], bi = lnb[e];
    const float r0 = (a0 - mean0) * rsqrtf(var0 + LNE) * sc + bi;
    const float r1 = (a1 - mean1) * rsqrtf(var1 + LNE) * sc + bi;
    const int h0 = t >> 6, h1 = h0 + 4;
    f16 h, l;
    split(r0, h, l);
    qh[((long)h0 * Qq + qi) * DH + e] = h;
    ql[((long)h0 * Qq + qi) * DH + e] = l;
    split(r1, h, l);
    qh[((long)h1 * Qq + qi) * DH + e] = h;
    ql[((long)h1 * Qq + qi) * DH + e] = l;
}

// ---------------------------------------------------------------------------
// out = EVN2(resiT @ w_out), fp32 store. One block per (b,q).
__global__ __launch_bounds__(256) void k_out(
    const float* __restrict__ resiT, const float* __restrict__ w_out,
    const float* __restrict__ w2a, const float* __restrict__ b2a,
    const float* __restrict__ w2b, const float* __restrict__ b2b,
    float* __restrict__ out)
{
    __shared__ float rs[Fv * Vd];
    __shared__ float norm_s[Vd];
    __shared__ float h_s[256];

    const int t = threadIdx.x;
    const long bq = blockIdx.x;
    const float* rp = resiT + bq * (Fv * Vd);
    for (int i = t; i < Fv * Vd; i += 256) rs[i] = rp[i];
    __syncthreads();

    float a0 = 0, a1 = 0, a2 = 0, a3 = 0, a4 = 0, a5 = 0;
    #pragma unroll 4
    for (int d = 0; d < Vd; ++d) {
        const float w0 = w_out[d * Vd + t];
        const float w1 = w_out[d * Vd + t + 256];
        const float x0 = rs[d], x1 = rs[Vd + d], x2 = rs[2 * Vd + d];
        a0 += x0 * w0; a1 += x1 * w0; a2 += x2 * w0;
        a3 += x0 * w1; a4 += x1 * w1; a5 += x2 * w1;
    }
    const float nrm0 = sqrtf(a0 * a0 + a1 * a1 + a2 * a2);
    const float nrm1 = sqrtf(a3 * a3 + a4 * a4 + a5 * a5);
    norm_s[t] = nrm0;
    norm_s[t + 256] = nrm1;
    __syncthreads();

    float hacc = b2a[t];
    #pragma unroll 4
    for (int d = 0; d < Vd; ++d) hacc += (norm_s[d] + EPS) * w2a[d * 256 + t];
    h_s[t] = hacc > 0.f ? hacc : NEG * hacc;
    __syncthreads();

    float g0 = b2b[t], g1 = b2b[t + 256];
    #pragma unroll 4
    for (int j = 0; j < 256; ++j) {
        const float hv = h_s[j];
        g0 += hv * w2b[j * Vd + t];
        g1 += hv * w2b[j * Vd + t + 256];
    }
    const float s0 = (nrm0 <= EPS) ? 1.f : g0 / (nrm0 + EPS);
    const float s1 = (nrm1 <= EPS) ? 1.f : g1 / (nrm1 + EPS);

    float* op = out + bq * (Fv * Vd);
    op[0 * Vd + t]       = a0 * s0;
    op[1 * Vd + t]       = a1 * s0;
    op[2 * Vd + t]       = a2 * s0;
    op[0 * Vd + t + 256] = a3 * s1;
    op[1 * Vd + t + 256] = a4 * s1;
    op[2 * Vd + t + 256] = a5 * s1;
}

// ---------------------------------------------------------------------------
extern "C" void kernel_launch(void* const* d_in, const int* in_sizes, int n_in,
                              void* d_out, int out_size, void* d_ws, size_t ws_size,
                              hipStream_t stream)
{
    const float* x    = (const float*)d_in[0];
    const float* lq   = (const float*)d_in[1];
    const float* w_kv = (const float*)d_in[2];
    const float* w1a  = (const float*)d_in[3];
    const float* b1a  = (const float*)d_in[4];
    const float* w1b  = (const float*)d_in[5];
    const float* b1b  = (const float*)d_in[6];
    const float* wq   = (const float*)d_in[7];
    const float* wk   = (const float*)d_in[8];
    const float* wv   = (const float*)d_in[9];
    const float* lqs  = (const float*)d_in[10];
    const float* lqb  = (const float*)d_in[11];
    const float* lks  = (const float*)d_in[12];
    const float* lkb  = (const float*)d_in[13];
    const float* wo   = (const float*)d_in[14];
    const float* w2a  = (const float*)d_in[15];
    const float* b2a  = (const float*)d_in[16];
    const float* w2b  = (const float*)d_in[17];
    const float* b2b  = (const float*)d_in[18];

    char* ws = (char*)d_ws;
    // Layout (191.5 MB, lifetime-aliased; FIXED R7's S-region overlap):
    //  W  [0, 3670016): weight pairs
    //  S  [3670016, 3817472): qhp 64K | qlp 64K | lsum 16K  (disjoint now)
    //  A1 [6946816, 40501248): normb pair -> kinv pair -> attn f32
    //  A2 [40501248, 57278464): hb pair -> resiT f32 (hb dead after step 5)
    //  B  [57278464, 157941760): kv pair (pre -> gated in-place)
    //  D  [157941760, 191496192): g f32 -> k pair -> U pair
    f16* wkvTh = (f16*)(ws + 0);
    f16* wkvTl = (f16*)(ws + 262144);
    f16* w1aTh = (f16*)(ws + 524288);
    f16* w1aTl = (f16*)(ws + 786432);
    f16* w1bTh = (f16*)(ws + 1048576);
    f16* w1bTl = (f16*)(ws + 1310720);
    f16* wkTh  = (f16*)(ws + 1572864);
    f16* wkTl  = (f16*)(ws + 2097152);
    f16* wvTh  = (f16*)(ws + 2621440);
    f16* wvTl  = (f16*)(ws + 3145728);
    f16*   qhp   = (f16*)(ws + 3670016);   // 65536 B
    f16*   qlp   = (f16*)(ws + 3735552);   // 65536 B
    float* lsum  = (float*)(ws + 3801088); // 16384 B
    f16* nh    = (f16*)(ws + 6946816);
    f16* nl    = (f16*)(ws + 23724032);
    f16* kih   = nh;
    f16* kil   = nl;
    float* attn = (float*)(ws + 6946816);
    f16* hbh   = (f16*)(ws + 40501248);
    f16* hbl   = (f16*)(ws + 48889856);
    float* resiT = (float*)(ws + 40501248); // aliases hb (dead after step 5)
    f16* kvh   = (f16*)(ws + 57278464);
    f16* kvl   = (f16*)(ws + 107610112);
    float* g    = (float*)(ws + 157941760);
    f16* khb   = (f16*)(ws + 157941760);
    f16* klb   = (f16*)(ws + 174718976);
    f16* Uh    = (f16*)(ws + 157941760);
    f16* Ul    = (f16*)(ws + 170524672);
    float* out  = (float*)d_out;

    // 1. weight casts (transposed pairs)
    k_castTpair<<<512,  256, 0, stream>>>(w_kv, wkvTh, wkvTl, Dd, QK);
    k_castTpair<<<512,  256, 0, stream>>>(w1a,  w1aTh, w1aTl, QK, 256);
    k_castTpair<<<512,  256, 0, stream>>>(w1b,  w1bTh, w1bTl, 256, QK);
    k_castTpair<<<1024, 256, 0, stream>>>(wk,   wkTh,  wkTl,  QK, QK);
    k_castTpair<<<1024, 256, 0, stream>>>(wv,   wvTh,  wvTl,  QK, QK);

    // 2. kv_pre = x @ w_kv   (A = fp32 x, split on the fly) -> kv pair
    k_gemm3<1, 0><<<dim3(384, 8), 256, 0, stream>>>(
        x, nullptr, nullptr, wkvTh, wkvTl, QK, Dd, kvh, kvl, nullptr, nullptr);
    // 3. norm
    k_norm<<<32768, 256, 0, stream>>>(kvh, kvl, nh, nl);
    // 4. h = leaky(norm @ w1a + b1a) -> hb pair
    k_gemm3<0, 1><<<dim3(128, 4), 256, 0, stream>>>(
        nullptr, nh, nl, w1aTh, w1aTl, 256, QK, hbh, hbl, b1a, nullptr);
    // 5. g = h @ w1b + b1b -> f32
    k_gemm3<0, 2><<<dim3(128, 8), 256, 0, stream>>>(
        nullptr, hbh, hbl, w1bTh, w1bTl, QK, 256, g, nullptr, b1b, nullptr);
    // 6. gate in-place + kinv pair
    k_gate<<<NT, 256, 0, stream>>>(kvh, kvl, g, kih, kil);
    // 7. k = LN(kinv @ wk) -> k pair [h][tok][64]
    k_gemm3<0, 3><<<dim3(128, 8), 256, 0, stream>>>(
        nullptr, kih, kil, wkTh, wkTl, QK, QK, khb, klb, lks, lkb);
    // 8. q -> pair
    k_qproj<<<Qq, 256, 0, stream>>>(lq, wq, lqs, lqb, qhp, qlp);
    // 9. attn: MFMA QK^T + exp + rowsum (unnormalized p, f32)
    k_attn_mfma<<<Hh * B, 256, 0, stream>>>(qhp, qlp, khb, klb, attn, lsum);
    // 10. U = (attn @ kv) / lsum -> U pair
    k_gemm3T<<<64 * 24, 256, 0, stream>>>(attn, kvh, kvl, lsum, Uh, Ul);
    // 11. resi = U @ wv -> resiT f32
    k_gemm3<0, 5><<<dim3(12, 8), 256, 0, stream>>>(
        nullptr, Uh, Ul, wvTh, wvTl, 64, QK, resiT, nullptr, nullptr, nullptr);
    // 12. out
    k_out<<<B * Qq, 256, 0, stream>>>(resiT, wo, w2a, b2a, w2b, b2b, out);
}

// Round 9
// 787.672 us; speedup vs baseline: 2.3321x; 1.0586x over previous
//
#include <hip/hip_runtime.h>
#include <hip/hip_bf16.h>

typedef _Float16 f16;
typedef __attribute__((ext_vector_type(8))) _Float16 f16x8;
typedef __attribute__((ext_vector_type(4))) _Float16 f16x4;
typedef __attribute__((ext_vector_type(2))) _Float16 f16x2;
typedef __attribute__((ext_vector_type(4))) float floatx4;

// Problem constants
constexpr int B  = 8;
constexpr int N  = 2048;
constexpr int Fv = 3;
constexpr int Dd = 256;
constexpr int QK = 512;
constexpr int Vd = 512;
constexpr int Hh = 8;
constexpr int Qq = 64;
constexpr int DH = 64;
constexpr int NT = B * N;          // 16384 tokens
constexpr float EPS = 1e-6f;
constexpr float NEG = 0.2f;
constexpr float LNE = 1e-6f;

#define DEV static __device__ __forceinline__
DEV void split(float v, f16& h, f16& l) { h = (f16)v; l = (f16)(v - (float)h); }

// ---------------------------------------------------------------------------
// Split-fp16 3-mul GEMM (effective fp32 accuracy): C = A[M,K] @ B[K,N]
// A as (Ah,Al) f16 pairs (ASRC=0) or fp32 split on the fly (ASRC=1).
// Bt = B^T row-major [N,K] as (Bh,Bl) pairs.
// Block 256 thr = 4 waves; tile 128M x 64N; wave = 32 rows x 64 cols.
// EPI: 0 pair store (kv_pre)        1 +bias,leaky -> pair (hb)
//      2 +bias -> f32 (g)           3 per-64col LN -> f16 pair [h][tok][64]
//      5 PV2: store f32 resiT[(b,q,f)][512] at col h*64+
// ---------------------------------------------------------------------------
template<int ASRC, int EPI>
__global__ __launch_bounds__(256) void k_gemm3(
    const float* __restrict__ A32,
    const f16* __restrict__ Ah, const f16* __restrict__ Al,
    const f16* __restrict__ Bh, const f16* __restrict__ Bl,
    int Ndim, int Kdim, void* __restrict__ C1, void* __restrict__ C2,
    const float* __restrict__ e0, const float* __restrict__ e1)
{
    __shared__ __align__(16) f16 Ash[128][72];
    __shared__ __align__(16) f16 Asl[128][72];
    __shared__ __align__(16) f16 Bsh[64][72];
    __shared__ __align__(16) f16 Bsl[64][72];

    const int t = threadIdx.x;
    long row0; int col0, boff;
    if (EPI == 5) { row0 = (long)blockIdx.y * 1536 + (long)blockIdx.x * 128; col0 = 0; boff = blockIdx.y * 64; }
    else          { row0 = (long)blockIdx.x * 128; col0 = blockIdx.y * 64; boff = 0; }

    floatx4 acc0[4], acc1[4];
    #pragma unroll
    for (int nt = 0; nt < 4; ++nt)
        #pragma unroll
        for (int j = 0; j < 4; ++j) { acc0[nt][j] = 0.f; acc1[nt][j] = 0.f; }

    const int L = t & 63, w = t >> 6;
    const int kq = (L >> 4) << 3;

    for (int k0 = 0; k0 < Kdim; k0 += 64) {
        if constexpr (ASRC == 1) {
            #pragma unroll
            for (int j = 0; j < 8; ++j) {
                const int i = t + j * 256;
                const int r = i >> 4, c4 = (i & 15) << 2;
                const floatx4 v = *(const floatx4*)&A32[(row0 + r) * Kdim + k0 + c4];
                f16x4 h4, l4;
                #pragma unroll
                for (int m = 0; m < 4; ++m) { h4[m] = (f16)v[m]; l4[m] = (f16)(v[m] - (float)h4[m]); }
                *(f16x4*)&Ash[r][c4] = h4;
                *(f16x4*)&Asl[r][c4] = l4;
            }
        } else {
            #pragma unroll
            for (int j = 0; j < 4; ++j) {
                const int i = t + j * 256;
                const int r = i >> 3, c8 = (i & 7) << 3;
                *(f16x8*)&Ash[r][c8] = *(const f16x8*)&Ah[(row0 + r) * (long)Kdim + k0 + c8];
                *(f16x8*)&Asl[r][c8] = *(const f16x8*)&Al[(row0 + r) * (long)Kdim + k0 + c8];
            }
        }
        #pragma unroll
        for (int j = 0; j < 2; ++j) {
            const int i = t + j * 256;
            const int r = i >> 3, c8 = (i & 7) << 3;
            *(f16x8*)&Bsh[r][c8] = *(const f16x8*)&Bh[(long)(boff + col0 + r) * Kdim + k0 + c8];
            *(f16x8*)&Bsl[r][c8] = *(const f16x8*)&Bl[(long)(boff + col0 + r) * Kdim + k0 + c8];
        }
        __syncthreads();
        #pragma unroll
        for (int kk = 0; kk < 64; kk += 32) {
            const f16x8 ah0 = *(const f16x8*)&Ash[w * 32 + (L & 15)][kk + kq];
            const f16x8 al0 = *(const f16x8*)&Asl[w * 32 + (L & 15)][kk + kq];
            const f16x8 ah1 = *(const f16x8*)&Ash[w * 32 + 16 + (L & 15)][kk + kq];
            const f16x8 al1 = *(const f16x8*)&Asl[w * 32 + 16 + (L & 15)][kk + kq];
            #pragma unroll
            for (int nt = 0; nt < 4; ++nt) {
                const f16x8 bh = *(const f16x8*)&Bsh[nt * 16 + (L & 15)][kk + kq];
                const f16x8 bl = *(const f16x8*)&Bsl[nt * 16 + (L & 15)][kk + kq];
                acc0[nt] = __builtin_amdgcn_mfma_f32_16x16x32_f16(ah0, bh, acc0[nt], 0, 0, 0);
                acc0[nt] = __builtin_amdgcn_mfma_f32_16x16x32_f16(ah0, bl, acc0[nt], 0, 0, 0);
                acc0[nt] = __builtin_amdgcn_mfma_f32_16x16x32_f16(al0, bh, acc0[nt], 0, 0, 0);
                acc1[nt] = __builtin_amdgcn_mfma_f32_16x16x32_f16(ah1, bh, acc1[nt], 0, 0, 0);
                acc1[nt] = __builtin_amdgcn_mfma_f32_16x16x32_f16(ah1, bl, acc1[nt], 0, 0, 0);
                acc1[nt] = __builtin_amdgcn_mfma_f32_16x16x32_f16(al1, bh, acc1[nt], 0, 0, 0);
            }
        }
        __syncthreads();
    }

    // C/D layout: col = lane&15, row = (lane>>4)*4 + reg
    const int cb = L & 15;
    #pragma unroll
    for (int rt = 0; rt < 2; ++rt) {
        const floatx4* acc = rt ? acc1 : acc0;
        const int rb = w * 32 + rt * 16 + ((L >> 4) << 2);
        if constexpr (EPI == 0) {
            f16* Ch = (f16*)C1; f16* Cl = (f16*)C2;
            #pragma unroll
            for (int nt = 0; nt < 4; ++nt)
                #pragma unroll
                for (int r = 0; r < 4; ++r) {
                    f16 h, l; split(acc[nt][r], h, l);
                    const long o = (row0 + rb + r) * (long)Ndim + col0 + nt * 16 + cb;
                    Ch[o] = h; Cl[o] = l;
                }
        } else if constexpr (EPI == 1) {
            f16* Ch = (f16*)C1; f16* Cl = (f16*)C2;
            #pragma unroll
            for (int nt = 0; nt < 4; ++nt) {
                const int col = col0 + nt * 16 + cb;
                const float bias = e0[col];
                #pragma unroll
                for (int r = 0; r < 4; ++r) {
                    float v = acc[nt][r] + bias;
                    v = v > 0.f ? v : NEG * v;
                    f16 h, l; split(v, h, l);
                    const long o = (row0 + rb + r) * (long)Ndim + col;
                    Ch[o] = h; Cl[o] = l;
                }
            }
        } else if constexpr (EPI == 2) {
            float* C = (float*)C1;
            #pragma unroll
            for (int nt = 0; nt < 4; ++nt) {
                const int col = col0 + nt * 16 + cb;
                const float bias = e0[col];
                #pragma unroll
                for (int r = 0; r < 4; ++r)
                    C[(row0 + rb + r) * (long)Ndim + col] = acc[nt][r] + bias;
            }
        } else if constexpr (EPI == 3) {
            f16* Ch = (f16*)C1; f16* Cl = (f16*)C2;
            const int h = blockIdx.y;
            #pragma unroll
            for (int r = 0; r < 4; ++r) {
                float s = 0.f, q = 0.f;
                #pragma unroll
                for (int nt = 0; nt < 4; ++nt) { const float v = acc[nt][r]; s += v; q += v * v; }
                s += __shfl_xor(s, 1); q += __shfl_xor(q, 1);
                s += __shfl_xor(s, 2); q += __shfl_xor(q, 2);
                s += __shfl_xor(s, 4); q += __shfl_xor(q, 4);
                s += __shfl_xor(s, 8); q += __shfl_xor(q, 8);
                const float mean = s * (1.f / 64.f);
                const float var  = q * (1.f / 64.f) - mean * mean;
                const float rs   = rsqrtf(var + LNE);
                #pragma unroll
                for (int nt = 0; nt < 4; ++nt) {
                    const int col = nt * 16 + cb;
                    const float v = (acc[nt][r] - mean) * rs * e0[col] + e1[col];
                    f16 hh, ll; split(v, hh, ll);
                    const long o = ((long)h * NT + row0 + rb + r) * 64 + col;
                    Ch[o] = hh; Cl[o] = ll;
                }
            }
        } else {  // EPI == 5
            float* C = (float*)C1;
            #pragma unroll
            for (int nt = 0; nt < 4; ++nt)
                #pragma unroll
                for (int r = 0; r < 4; ++r) {
                    const long rr = row0 + rb + r - (long)blockIdx.y * 1536;
                    C[rr * 512 + boff + nt * 16 + cb] = acc[nt][r];
                }
        }
    }
}

// ---------------------------------------------------------------------------
// Attention scores via MFMA, one block per hb = h*B+b.
// S[q,n] = (qv . k)/8 ; p = exp(S) (no max-sub: |S|<=8 after LN);
// store p (f32, unnormalized) + row sums lsum. Normalization folded into PV.
// ---------------------------------------------------------------------------
__global__ __launch_bounds__(256) void k_attn_mfma(
    const f16* __restrict__ qh, const f16* __restrict__ ql,
    const f16* __restrict__ kh, const f16* __restrict__ kl,
    float* __restrict__ attn, float* __restrict__ lsum)
{
    __shared__ __align__(16) f16 Qh[64][72], Ql[64][72];
    __shared__ __align__(16) f16 Kh[64][72], Kl[64][72];

    const int t = threadIdx.x;
    const int hb = blockIdx.x;
    const int h = hb >> 3;
    const int L = t & 63, w = t >> 6;
    const int kq = (L >> 4) << 3;

    // stage Q (64 q-rows x 64 e)
    #pragma unroll
    for (int j = 0; j < 2; ++j) {
        const int i = t + j * 256;
        const int r = i >> 3, c8 = (i & 7) << 3;
        *(f16x8*)&Qh[r][c8] = *(const f16x8*)&qh[((long)h * 64 + r) * 64 + c8];
        *(f16x8*)&Ql[r][c8] = *(const f16x8*)&ql[((long)h * 64 + r) * 64 + c8];
    }
    __syncthreads();

    // persistent A-frags: wave w owns q-rows w*16..w*16+15
    f16x8 qah[2], qal[2];
    #pragma unroll
    for (int kc = 0; kc < 2; ++kc) {
        qah[kc] = *(const f16x8*)&Qh[w * 16 + (L & 15)][kc * 32 + kq];
        qal[kc] = *(const f16x8*)&Ql[w * 16 + (L & 15)][kc * 32 + kq];
    }

    float psum[4] = {0.f, 0.f, 0.f, 0.f};
    const int rowb = w * 16 + ((L >> 4) << 2);

    for (int n0 = 0; n0 < N; n0 += 64) {
        __syncthreads();
        #pragma unroll
        for (int j = 0; j < 2; ++j) {
            const int i = t + j * 256;
            const int r = i >> 3, c8 = (i & 7) << 3;
            *(f16x8*)&Kh[r][c8] = *(const f16x8*)&kh[((long)hb * N + n0 + r) * 64 + c8];
            *(f16x8*)&Kl[r][c8] = *(const f16x8*)&kl[((long)hb * N + n0 + r) * 64 + c8];
        }
        __syncthreads();

        floatx4 acc[4];
        #pragma unroll
        for (int nt = 0; nt < 4; ++nt)
            #pragma unroll
            for (int j = 0; j < 4; ++j) acc[nt][j] = 0.f;

        #pragma unroll
        for (int kc = 0; kc < 2; ++kc) {
            #pragma unroll
            for (int nt = 0; nt < 4; ++nt) {
                const f16x8 bh = *(const f16x8*)&Kh[nt * 16 + (L & 15)][kc * 32 + kq];
                const f16x8 bl = *(const f16x8*)&Kl[nt * 16 + (L & 15)][kc * 32 + kq];
                acc[nt] = __builtin_amdgcn_mfma_f32_16x16x32_f16(qah[kc], bh, acc[nt], 0, 0, 0);
                acc[nt] = __builtin_amdgcn_mfma_f32_16x16x32_f16(qah[kc], bl, acc[nt], 0, 0, 0);
                acc[nt] = __builtin_amdgcn_mfma_f32_16x16x32_f16(qal[kc], bh, acc[nt], 0, 0, 0);
            }
        }

        #pragma unroll
        for (int nt = 0; nt < 4; ++nt)
            #pragma unroll
            for (int r = 0; r < 4; ++r) {
                const float p = __expf(acc[nt][r] * 0.125f);
                psum[r] += p;
                attn[((long)hb * 64 + rowb + r) * N + n0 + nt * 16 + (L & 15)] = p;
            }
    }

    // reduce row sums across the 16 lanes sharing each row
    #pragma unroll
    for (int r = 0; r < 4; ++r) {
        float s = psum[r];
        s += __shfl_xor(s, 1);
        s += __shfl_xor(s, 2);
        s += __shfl_xor(s, 4);
        s += __shfl_xor(s, 8);
        if ((L & 15) == 0) lsum[hb * 64 + rowb + r] = s;
    }
}

// ---------------------------------------------------------------------------
// PV1: U[hb*64+q, fd] = (1/lsum[row]) * sum_n p[row,n] * kv[b][n, fd]
// A = unnormalized attn f32 (split on the fly); B = kv pair, K-major
// (row n, stride 1536) transposed into LDS. Output U pair.
// Grid is ct-major so same-(b,ct) blocks co-schedule (kv served from L2);
// B-stage thread map (k2=t&31, c8=(t>>5)<<3) makes LDS stores 2-way (free).
// ---------------------------------------------------------------------------
__global__ __launch_bounds__(256) void k_gemm3T(
    const float* __restrict__ A32,
    const f16* __restrict__ Bh, const f16* __restrict__ Bl,
    const float* __restrict__ lsum,
    f16* __restrict__ Uh, f16* __restrict__ Ul)
{
    __shared__ __align__(16) f16 Ash[64][72];
    __shared__ __align__(16) f16 Asl[64][72];
    __shared__ __align__(16) f16 Bsh[64][72];
    __shared__ __align__(16) f16 Bsl[64][72];

    const int t = threadIdx.x;
    const int by = blockIdx.x;
    const int hb = by & 63, ct = by >> 6;   // ct-major grid for L2 kv reuse
    const int b = hb & 7;
    const float* Ab = A32 + (long)hb * 64 * 2048;
    const f16* Bbh = Bh + (long)b * 2048 * 1536 + ct * 64;
    const f16* Bbl = Bl + (long)b * 2048 * 1536 + ct * 64;

    floatx4 acc[4];
    #pragma unroll
    for (int nt = 0; nt < 4; ++nt)
        #pragma unroll
        for (int j = 0; j < 4; ++j) acc[nt][j] = 0.f;

    const int L = t & 63, w = t >> 6;
    const int kq = (L >> 4) << 3;
    const int k2 = t & 31, c8 = (t >> 5) << 3;   // B-transpose map: 2-way banks

    for (int k0 = 0; k0 < 2048; k0 += 64) {
        #pragma unroll
        for (int j = 0; j < 4; ++j) {
            const int i = t + j * 256;
            const int r = i >> 4, c4 = (i & 15) << 2;
            const floatx4 v = *(const floatx4*)&Ab[(long)r * 2048 + k0 + c4];
            f16x4 h4, l4;
            #pragma unroll
            for (int m = 0; m < 4; ++m) { h4[m] = (f16)v[m]; l4[m] = (f16)(v[m] - (float)h4[m]); }
            *(f16x4*)&Ash[r][c4] = h4;
            *(f16x4*)&Asl[r][c4] = l4;
        }
        {
            const f16x8 r0h = *(const f16x8*)&Bbh[(long)(k0 + 2 * k2) * 1536 + c8];
            const f16x8 r1h = *(const f16x8*)&Bbh[(long)(k0 + 2 * k2 + 1) * 1536 + c8];
            const f16x8 r0l = *(const f16x8*)&Bbl[(long)(k0 + 2 * k2) * 1536 + c8];
            const f16x8 r1l = *(const f16x8*)&Bbl[(long)(k0 + 2 * k2 + 1) * 1536 + c8];
            #pragma unroll
            for (int j = 0; j < 8; ++j) {
                f16x2 ph; ph[0] = r0h[j]; ph[1] = r1h[j];
                f16x2 pl; pl[0] = r0l[j]; pl[1] = r1l[j];
                *(f16x2*)&Bsh[c8 + j][2 * k2] = ph;
                *(f16x2*)&Bsl[c8 + j][2 * k2] = pl;
            }
        }
        __syncthreads();
        #pragma unroll
        for (int kk = 0; kk < 64; kk += 32) {
            const f16x8 ah0 = *(const f16x8*)&Ash[w * 16 + (L & 15)][kk + kq];
            const f16x8 al0 = *(const f16x8*)&Asl[w * 16 + (L & 15)][kk + kq];
            #pragma unroll
            for (int nt = 0; nt < 4; ++nt) {
                const f16x8 bh = *(const f16x8*)&Bsh[nt * 16 + (L & 15)][kk + kq];
                const f16x8 bl = *(const f16x8*)&Bsl[nt * 16 + (L & 15)][kk + kq];
                acc[nt] = __builtin_amdgcn_mfma_f32_16x16x32_f16(ah0, bh, acc[nt], 0, 0, 0);
                acc[nt] = __builtin_amdgcn_mfma_f32_16x16x32_f16(ah0, bl, acc[nt], 0, 0, 0);
                acc[nt] = __builtin_amdgcn_mfma_f32_16x16x32_f16(al0, bh, acc[nt], 0, 0, 0);
            }
        }
        __syncthreads();
    }

    const int cb = L & 15;
    const int rb = w * 16 + ((L >> 4) << 2);
    #pragma unroll
    for (int r = 0; r < 4; ++r) {
        const float inv = 1.f / lsum[hb * 64 + rb + r];
        #pragma unroll
        for (int nt = 0; nt < 4; ++nt) {
            f16 h, l; split(acc[nt][r] * inv, h, l);
            const long o = ((long)hb * 64 + rb + r) * 1536 + ct * 64 + nt * 16 + cb;
            Uh[o] = h; Ul[o] = l;
        }
    }
}

// ---------------------------------------------------------------------------
// f32 [K,N] -> transposed f16 pair [N,K]
__global__ void k_castTpair(const float* __restrict__ s, f16* __restrict__ dh,
                            f16* __restrict__ dl, int K, int Nn)
{
    const long i = (long)blockIdx.x * 256 + threadIdx.x;
    if (i >= (long)K * Nn) return;
    const int k = (int)(i / Nn), n = (int)(i - (long)k * Nn);
    f16 h, l; split(s[i], h, l);
    dh[(long)n * K + k] = h;
    dl[(long)n * K + k] = l;
}

// normb pair = f16pair( sqrt(sum_f kv_pre^2) + EPS ), one thread per (tk,c)
__global__ void k_norm(const f16* __restrict__ kh, const f16* __restrict__ kl,
                       f16* __restrict__ nh, f16* __restrict__ nl)
{
    const long i = (long)blockIdx.x * 256 + threadIdx.x;
    const int tk = (int)(i >> 9), c = (int)(i & 511);
    const long base = (long)tk * 1536 + c;
    const float a = (float)kh[base]        + (float)kl[base];
    const float b = (float)kh[base + 512]  + (float)kl[base + 512];
    const float cc = (float)kh[base + 1024] + (float)kl[base + 1024];
    f16 h, l; split(sqrtf(a * a + b * b + cc * cc) + EPS, h, l);
    nh[i] = h; nl[i] = l;
}

// gate (in-place on kv pair) + kinv pair. One block per token.
__global__ __launch_bounds__(256) void k_gate(
    f16* __restrict__ kh, f16* __restrict__ kl, const float* __restrict__ g,
    f16* __restrict__ kih, f16* __restrict__ kil)
{
    __shared__ float red[3][4];
    const int t = threadIdx.x;
    const int tk = blockIdx.x;
    float kv[2][3];
    float ps0 = 0.f, ps1 = 0.f, ps2 = 0.f;
    #pragma unroll
    for (int j = 0; j < 2; ++j) {
        const int c = t + j * 256;
        const long base = (long)tk * 1536 + c;
        const float k0 = (float)kh[base]        + (float)kl[base];
        const float k1 = (float)kh[base + 512]  + (float)kl[base + 512];
        const float k2 = (float)kh[base + 1024] + (float)kl[base + 1024];
        const float nr = sqrtf(k0 * k0 + k1 * k1 + k2 * k2);
        const float gv = g[(long)tk * 512 + c];
        const float s = (nr <= EPS) ? 1.f : gv / (nr + EPS);
        kv[j][0] = k0 * s; kv[j][1] = k1 * s; kv[j][2] = k2 * s;
        f16 h, l;
        split(kv[j][0], h, l); kh[base] = h;        kl[base] = l;
        split(kv[j][1], h, l); kh[base + 512] = h;  kl[base + 512] = l;
        split(kv[j][2], h, l); kh[base + 1024] = h; kl[base + 1024] = l;
        ps0 += kv[j][0]; ps1 += kv[j][1]; ps2 += kv[j][2];
    }
    for (int off = 32; off; off >>= 1) {
        ps0 += __shfl_down(ps0, off);
        ps1 += __shfl_down(ps1, off);
        ps2 += __shfl_down(ps2, off);
    }
    if ((t & 63) == 0) { red[0][t >> 6] = ps0; red[1][t >> 6] = ps1; red[2][t >> 6] = ps2; }
    __syncthreads();
    const float m0 = (red[0][0] + red[0][1] + red[0][2] + red[0][3]) * (1.f / 512.f);
    const float m1 = (red[1][0] + red[1][1] + red[1][2] + red[1][3]) * (1.f / 512.f);
    const float m2 = (red[2][0] + red[2][1] + red[2][2] + red[2][3]) * (1.f / 512.f);
    #pragma unroll
    for (int j = 0; j < 2; ++j) {
        const int c = t + j * 256;
        f16 h, l; split(kv[j][0] * m0 + kv[j][1] * m1 + kv[j][2] * m2, h, l);
        kih[(long)tk * 512 + c] = h;
        kil[(long)tk * 512 + c] = l;
    }
}

// ---------------------------------------------------------------------------
// q = LN(lq @ wq) per head (fp32 VALU, tiny), output f16 pair [h][qi][64].
__global__ __launch_bounds__(256) void k_qproj(
    const float* __restrict__ lq, const float* __restrict__ wq,
    const float* __restrict__ lns, const float* __restrict__ lnb,
    f16* __restrict__ qh, f16* __restrict__ ql)
{
    __shared__ float cs[QK];
    const int t = threadIdx.x;
    const int qi = blockIdx.x;
    const float* cp = lq + (long)qi * QK;
    for (int i = t; i < QK; i += 256) cs[i] = cp[i];
    __syncthreads();

    float a0 = 0, a1 = 0;
    #pragma unroll 4
    for (int d = 0; d < QK; ++d) {
        const float c = cs[d];
        a0 += c * wq[d * QK + t];
        a1 += c * wq[d * QK + t + 256];
    }
    float s0 = a0, q0 = a0 * a0, s1 = a1, q1 = a1 * a1;
    for (int off = 32; off; off >>= 1) {
        s0 += __shfl_down(s0, off); q0 += __shfl_down(q0, off);
        s1 += __shfl_down(s1, off); q1 += __shfl_down(q1, off);
    }
    s0 = __shfl(s0, 0); q0 = __shfl(q0, 0);
    s1 = __shfl(s1, 0); q1 = __shfl(q1, 0);
    const float mean0 = s0 * (1.f / 64.f), var0 = q0 * (1.f / 64.f) - mean0 * mean0;
    const float mean1 = s1 * (1.f / 64.f), var1 = q1 * (1.f / 64.f) - mean1 * mean1;
    const int e = t & 63;
    const float sc = lns[e], bi = lnb[e];
    const float r0 = (a0 - mean0) * rsqrtf(var0 + LNE) * sc + bi;
    const float r1 = (a1 - mean1) * rsqrtf(var1 + LNE) * sc + bi;
    const int h0 = t >> 6, h1 = h0 + 4;
    f16 h, l;
    split(r0, h, l);
    qh[((long)h0 * Qq + qi) * DH + e] = h;
    ql[((long)h0 * Qq + qi) * DH + e] = l;
    split(r1, h, l);
    qh[((long)h1 * Qq + qi) * DH + e] = h;
    ql[((long)h1 * Qq + qi) * DH + e] = l;
}

// ---------------------------------------------------------------------------
// out = EVN2(resiT @ w_out), fp32 store. One block per (b,q).
__global__ __launch_bounds__(256) void k_out(
    const float* __restrict__ resiT, const float* __restrict__ w_out,
    const float* __restrict__ w2a, const float* __restrict__ b2a,
    const float* __restrict__ w2b, const float* __restrict__ b2b,
    float* __restrict__ out)
{
    __shared__ float rs[Fv * Vd];
    __shared__ float norm_s[Vd];
    __shared__ float h_s[256];

    const int t = threadIdx.x;
    const long bq = blockIdx.x;
    const float* rp = resiT + bq * (Fv * Vd);
    for (int i = t; i < Fv * Vd; i += 256) rs[i] = rp[i];
    __syncthreads();

    float a0 = 0, a1 = 0, a2 = 0, a3 = 0, a4 = 0, a5 = 0;
    #pragma unroll 4
    for (int d = 0; d < Vd; ++d) {
        const float w0 = w_out[d * Vd + t];
        const float w1 = w_out[d * Vd + t + 256];
        const float x0 = rs[d], x1 = rs[Vd + d], x2 = rs[2 * Vd + d];
        a0 += x0 * w0; a1 += x1 * w0; a2 += x2 * w0;
        a3 += x0 * w1; a4 += x1 * w1; a5 += x2 * w1;
    }
    const float nrm0 = sqrtf(a0 * a0 + a1 * a1 + a2 * a2);
    const float nrm1 = sqrtf(a3 * a3 + a4 * a4 + a5 * a5);
    norm_s[t] = nrm0;
    norm_s[t + 256] = nrm1;
    __syncthreads();

    float hacc = b2a[t];
    #pragma unroll 4
    for (int d = 0; d < Vd; ++d) hacc += (norm_s[d] + EPS) * w2a[d * 256 + t];
    h_s[t] = hacc > 0.f ? hacc : NEG * hacc;
    __syncthreads();

    float g0 = b2b[t], g1 = b2b[t + 256];
    #pragma unroll 4
    for (int j = 0; j < 256; ++j) {
        const float hv = h_s[j];
        g0 += hv * w2b[j * Vd + t];
        g1 += hv * w2b[j * Vd + t + 256];
    }
    const float s0 = (nrm0 <= EPS) ? 1.f : g0 / (nrm0 + EPS);
    const float s1 = (nrm1 <= EPS) ? 1.f : g1 / (nrm1 + EPS);

    float* op = out + bq * (Fv * Vd);
    op[0 * Vd + t]       = a0 * s0;
    op[1 * Vd + t]       = a1 * s0;
    op[2 * Vd + t]       = a2 * s0;
    op[0 * Vd + t + 256] = a3 * s1;
    op[1 * Vd + t + 256] = a4 * s1;
    op[2 * Vd + t + 256] = a5 * s1;
}

// ---------------------------------------------------------------------------
extern "C" void kernel_launch(void* const* d_in, const int* in_sizes, int n_in,
                              void* d_out, int out_size, void* d_ws, size_t ws_size,
                              hipStream_t stream)
{
    const float* x    = (const float*)d_in[0];
    const float* lq   = (const float*)d_in[1];
    const float* w_kv = (const float*)d_in[2];
    const float* w1a  = (const float*)d_in[3];
    const float* b1a  = (const float*)d_in[4];
    const float* w1b  = (const float*)d_in[5];
    const float* b1b  = (const float*)d_in[6];
    const float* wq   = (const float*)d_in[7];
    const float* wk   = (const float*)d_in[8];
    const float* wv   = (const float*)d_in[9];
    const float* lqs  = (const float*)d_in[10];
    const float* lqb  = (const float*)d_in[11];
    const float* lks  = (const float*)d_in[12];
    const float* lkb  = (const float*)d_in[13];
    const float* wo   = (const float*)d_in[14];
    const float* w2a  = (const float*)d_in[15];
    const float* b2a  = (const float*)d_in[16];
    const float* w2b  = (const float*)d_in[17];
    const float* b2b  = (const float*)d_in[18];

    char* ws = (char*)d_ws;
    // Layout (191.5 MB, lifetime-aliased):
    //  W  [0, 3670016): weight pairs
    //  S  [3670016, 3817472): qhp 64K | qlp 64K | lsum 16K
    //  A1 [6946816, 40501248): normb pair -> kinv pair -> attn f32
    //  A2 [40501248, 57278464): hb pair -> resiT f32 (hb dead after step 5)
    //  B  [57278464, 157941760): kv pair (pre -> gated in-place)
    //  D  [157941760, 191496192): g f32 -> k pair -> U pair
    f16* wkvTh = (f16*)(ws + 0);
    f16* wkvTl = (f16*)(ws + 262144);
    f16* w1aTh = (f16*)(ws + 524288);
    f16* w1aTl = (f16*)(ws + 786432);
    f16* w1bTh = (f16*)(ws + 1048576);
    f16* w1bTl = (f16*)(ws + 1310720);
    f16* wkTh  = (f16*)(ws + 1572864);
    f16* wkTl  = (f16*)(ws + 2097152);
    f16* wvTh  = (f16*)(ws + 2621440);
    f16* wvTl  = (f16*)(ws + 3145728);
    f16*   qhp   = (f16*)(ws + 3670016);   // 65536 B
    f16*   qlp   = (f16*)(ws + 3735552);   // 65536 B
    float* lsum  = (float*)(ws + 3801088); // 16384 B
    f16* nh    = (f16*)(ws + 6946816);
    f16* nl    = (f16*)(ws + 23724032);
    f16* kih   = nh;
    f16* kil   = nl;
    float* attn = (float*)(ws + 6946816);
    f16* hbh   = (f16*)(ws + 40501248);
    f16* hbl   = (f16*)(ws + 48889856);
    float* resiT = (float*)(ws + 40501248); // aliases hb (dead after step 5)
    f16* kvh   = (f16*)(ws + 57278464);
    f16* kvl   = (f16*)(ws + 107610112);
    float* g    = (float*)(ws + 157941760);
    f16* khb   = (f16*)(ws + 157941760);
    f16* klb   = (f16*)(ws + 174718976);
    f16* Uh    = (f16*)(ws + 157941760);
    f16* Ul    = (f16*)(ws + 170524672);
    float* out  = (float*)d_out;

    // 1. weight casts (transposed pairs)
    k_castTpair<<<512,  256, 0, stream>>>(w_kv, wkvTh, wkvTl, Dd, QK);
    k_castTpair<<<512,  256, 0, stream>>>(w1a,  w1aTh, w1aTl, QK, 256);
    k_castTpair<<<512,  256, 0, stream>>>(w1b,  w1bTh, w1bTl, 256, QK);
    k_castTpair<<<1024, 256, 0, stream>>>(wk,   wkTh,  wkTl,  QK, QK);
    k_castTpair<<<1024, 256, 0, stream>>>(wv,   wvTh,  wvTl,  QK, QK);

    // 2. kv_pre = x @ w_kv   (A = fp32 x, split on the fly) -> kv pair
    k_gemm3<1, 0><<<dim3(384, 8), 256, 0, stream>>>(
        x, nullptr, nullptr, wkvTh, wkvTl, QK, Dd, kvh, kvl, nullptr, nullptr);
    // 3. norm
    k_norm<<<32768, 256, 0, stream>>>(kvh, kvl, nh, nl);
    // 4. h = leaky(norm @ w1a + b1a) -> hb pair
    k_gemm3<0, 1><<<dim3(128, 4), 256, 0, stream>>>(
        nullptr, nh, nl, w1aTh, w1aTl, 256, QK, hbh, hbl, b1a, nullptr);
    // 5. g = h @ w1b + b1b -> f32
    k_gemm3<0, 2><<<dim3(128, 8), 256, 0, stream>>>(
        nullptr, hbh, hbl, w1bTh, w1bTl, QK, 256, g, nullptr, b1b, nullptr);
    // 6. gate in-place + kinv pair
    k_gate<<<NT, 256, 0, stream>>>(kvh, kvl, g, kih, kil);
    // 7. k = LN(kinv @ wk) -> k pair [h][tok][64]
    k_gemm3<0, 3><<<dim3(128, 8), 256, 0, stream>>>(
        nullptr, kih, kil, wkTh, wkTl, QK, QK, khb, klb, lks, lkb);
    // 8. q -> pair
    k_qproj<<<Qq, 256, 0, stream>>>(lq, wq, lqs, lqb, qhp, qlp);
    // 9. attn: MFMA QK^T + exp + rowsum (unnormalized p, f32)
    k_attn_mfma<<<Hh * B, 256, 0, stream>>>(qhp, qlp, khb, klb, attn, lsum);
    // 10. U = (attn @ kv) / lsum -> U pair
    k_gemm3T<<<64 * 24, 256, 0, stream>>>(attn, kvh, kvl, lsum, Uh, Ul);
    // 11. resi = U @ wv -> resiT f32
    k_gemm3<0, 5><<<dim3(12, 8), 256, 0, stream>>>(
        nullptr, Uh, Ul, wvTh, wvTl, 64, QK, resiT, nullptr, nullptr, nullptr);
    // 12. out
    k_out<<<B * Qq, 256, 0, stream>>>(resiT, wo, w2a, b2a, w2b, b2b, out);
}

// Round 10
// 735.449 us; speedup vs baseline: 2.4977x; 1.0710x over previous
//
#include <hip/hip_runtime.h>
#include <hip/hip_bf16.h>

typedef _Float16 f16;
typedef __attribute__((ext_vector_type(8))) _Float16 f16x8;
typedef __attribute__((ext_vector_type(4))) _Float16 f16x4;
typedef __attribute__((ext_vector_type(2))) _Float16 f16x2;
typedef __attribute__((ext_vector_type(4))) float floatx4;

// Problem constants
constexpr int B  = 8;
constexpr int N  = 2048;
constexpr int Fv = 3;
constexpr int Dd = 256;
constexpr int QK = 512;
constexpr int Vd = 512;
constexpr int Hh = 8;
constexpr int Qq = 64;
constexpr int DH = 64;
constexpr int NT = B * N;          // 16384 tokens
constexpr float EPS = 1e-6f;
constexpr float NEG = 0.2f;
constexpr float LNE = 1e-6f;

#define DEV static __device__ __forceinline__
DEV void split(float v, f16& h, f16& l) { h = (f16)v; l = (f16)(v - (float)h); }

// ---------------------------------------------------------------------------
// Split-fp16 3-mul GEMM (effective fp32 accuracy): C = A[M,K] @ B[K,N]
// A as (Ah,Al) f16 pairs (ASRC=0) or fp32 split on the fly (ASRC=1).
// Bt = B^T row-major [N,K] as (Bh,Bl) pairs.
// Block 256 thr = 4 waves; tile 128M x 64N; wave = 32 rows x 64 cols.
// EPI: 0 pair store (kv_pre)        1 +bias,leaky -> pair (hb)
//      2 +bias -> f32 (g)           3 per-64col LN -> f16 pair [h][tok][64]
//      5 PV2: store f32 resiT[(b,q,f)][512] at col h*64+
// ---------------------------------------------------------------------------
template<int ASRC, int EPI>
__global__ __launch_bounds__(256) void k_gemm3(
    const float* __restrict__ A32,
    const f16* __restrict__ Ah, const f16* __restrict__ Al,
    const f16* __restrict__ Bh, const f16* __restrict__ Bl,
    int Ndim, int Kdim, void* __restrict__ C1, void* __restrict__ C2,
    const float* __restrict__ e0, const float* __restrict__ e1)
{
    __shared__ __align__(16) f16 Ash[128][72];
    __shared__ __align__(16) f16 Asl[128][72];
    __shared__ __align__(16) f16 Bsh[64][72];
    __shared__ __align__(16) f16 Bsl[64][72];

    const int t = threadIdx.x;
    long row0; int col0, boff;
    if (EPI == 5) { row0 = (long)blockIdx.y * 1536 + (long)blockIdx.x * 128; col0 = 0; boff = blockIdx.y * 64; }
    else          { row0 = (long)blockIdx.x * 128; col0 = blockIdx.y * 64; boff = 0; }

    floatx4 acc0[4], acc1[4];
    #pragma unroll
    for (int nt = 0; nt < 4; ++nt)
        #pragma unroll
        for (int j = 0; j < 4; ++j) { acc0[nt][j] = 0.f; acc1[nt][j] = 0.f; }

    const int L = t & 63, w = t >> 6;
    const int kq = (L >> 4) << 3;

    for (int k0 = 0; k0 < Kdim; k0 += 64) {
        if constexpr (ASRC == 1) {
            #pragma unroll
            for (int j = 0; j < 8; ++j) {
                const int i = t + j * 256;
                const int r = i >> 4, c4 = (i & 15) << 2;
                const floatx4 v = *(const floatx4*)&A32[(row0 + r) * Kdim + k0 + c4];
                f16x4 h4, l4;
                #pragma unroll
                for (int m = 0; m < 4; ++m) { h4[m] = (f16)v[m]; l4[m] = (f16)(v[m] - (float)h4[m]); }
                *(f16x4*)&Ash[r][c4] = h4;
                *(f16x4*)&Asl[r][c4] = l4;
            }
        } else {
            #pragma unroll
            for (int j = 0; j < 4; ++j) {
                const int i = t + j * 256;
                const int r = i >> 3, c8 = (i & 7) << 3;
                *(f16x8*)&Ash[r][c8] = *(const f16x8*)&Ah[(row0 + r) * (long)Kdim + k0 + c8];
                *(f16x8*)&Asl[r][c8] = *(const f16x8*)&Al[(row0 + r) * (long)Kdim + k0 + c8];
            }
        }
        #pragma unroll
        for (int j = 0; j < 2; ++j) {
            const int i = t + j * 256;
            const int r = i >> 3, c8 = (i & 7) << 3;
            *(f16x8*)&Bsh[r][c8] = *(const f16x8*)&Bh[(long)(boff + col0 + r) * Kdim + k0 + c8];
            *(f16x8*)&Bsl[r][c8] = *(const f16x8*)&Bl[(long)(boff + col0 + r) * Kdim + k0 + c8];
        }
        __syncthreads();
        #pragma unroll
        for (int kk = 0; kk < 64; kk += 32) {
            const f16x8 ah0 = *(const f16x8*)&Ash[w * 32 + (L & 15)][kk + kq];
            const f16x8 al0 = *(const f16x8*)&Asl[w * 32 + (L & 15)][kk + kq];
            const f16x8 ah1 = *(const f16x8*)&Ash[w * 32 + 16 + (L & 15)][kk + kq];
            const f16x8 al1 = *(const f16x8*)&Asl[w * 32 + 16 + (L & 15)][kk + kq];
            #pragma unroll
            for (int nt = 0; nt < 4; ++nt) {
                const f16x8 bh = *(const f16x8*)&Bsh[nt * 16 + (L & 15)][kk + kq];
                const f16x8 bl = *(const f16x8*)&Bsl[nt * 16 + (L & 15)][kk + kq];
                acc0[nt] = __builtin_amdgcn_mfma_f32_16x16x32_f16(ah0, bh, acc0[nt], 0, 0, 0);
                acc0[nt] = __builtin_amdgcn_mfma_f32_16x16x32_f16(ah0, bl, acc0[nt], 0, 0, 0);
                acc0[nt] = __builtin_amdgcn_mfma_f32_16x16x32_f16(al0, bh, acc0[nt], 0, 0, 0);
                acc1[nt] = __builtin_amdgcn_mfma_f32_16x16x32_f16(ah1, bh, acc1[nt], 0, 0, 0);
                acc1[nt] = __builtin_amdgcn_mfma_f32_16x16x32_f16(ah1, bl, acc1[nt], 0, 0, 0);
                acc1[nt] = __builtin_amdgcn_mfma_f32_16x16x32_f16(al1, bh, acc1[nt], 0, 0, 0);
            }
        }
        __syncthreads();
    }

    // C/D layout: col = lane&15, row = (lane>>4)*4 + reg
    const int cb = L & 15;
    #pragma unroll
    for (int rt = 0; rt < 2; ++rt) {
        const floatx4* acc = rt ? acc1 : acc0;
        const int rb = w * 32 + rt * 16 + ((L >> 4) << 2);
        if constexpr (EPI == 0) {
            f16* Ch = (f16*)C1; f16* Cl = (f16*)C2;
            #pragma unroll
            for (int nt = 0; nt < 4; ++nt)
                #pragma unroll
                for (int r = 0; r < 4; ++r) {
                    f16 h, l; split(acc[nt][r], h, l);
                    const long o = (row0 + rb + r) * (long)Ndim + col0 + nt * 16 + cb;
                    Ch[o] = h; Cl[o] = l;
                }
        } else if constexpr (EPI == 1) {
            f16* Ch = (f16*)C1; f16* Cl = (f16*)C2;
            #pragma unroll
            for (int nt = 0; nt < 4; ++nt) {
                const int col = col0 + nt * 16 + cb;
                const float bias = e0[col];
                #pragma unroll
                for (int r = 0; r < 4; ++r) {
                    float v = acc[nt][r] + bias;
                    v = v > 0.f ? v : NEG * v;
                    f16 h, l; split(v, h, l);
                    const long o = (row0 + rb + r) * (long)Ndim + col;
                    Ch[o] = h; Cl[o] = l;
                }
            }
        } else if constexpr (EPI == 2) {
            float* C = (float*)C1;
            #pragma unroll
            for (int nt = 0; nt < 4; ++nt) {
                const int col = col0 + nt * 16 + cb;
                const float bias = e0[col];
                #pragma unroll
                for (int r = 0; r < 4; ++r)
                    C[(row0 + rb + r) * (long)Ndim + col] = acc[nt][r] + bias;
            }
        } else if constexpr (EPI == 3) {
            f16* Ch = (f16*)C1; f16* Cl = (f16*)C2;
            const int h = blockIdx.y;
            #pragma unroll
            for (int r = 0; r < 4; ++r) {
                float s = 0.f, q = 0.f;
                #pragma unroll
                for (int nt = 0; nt < 4; ++nt) { const float v = acc[nt][r]; s += v; q += v * v; }
                s += __shfl_xor(s, 1); q += __shfl_xor(q, 1);
                s += __shfl_xor(s, 2); q += __shfl_xor(q, 2);
                s += __shfl_xor(s, 4); q += __shfl_xor(q, 4);
                s += __shfl_xor(s, 8); q += __shfl_xor(q, 8);
                const float mean = s * (1.f / 64.f);
                const float var  = q * (1.f / 64.f) - mean * mean;
                const float rs   = rsqrtf(var + LNE);
                #pragma unroll
                for (int nt = 0; nt < 4; ++nt) {
                    const int col = nt * 16 + cb;
                    const float v = (acc[nt][r] - mean) * rs * e0[col] + e1[col];
                    f16 hh, ll; split(v, hh, ll);
                    const long o = ((long)h * NT + row0 + rb + r) * 64 + col;
                    Ch[o] = hh; Cl[o] = ll;
                }
            }
        } else {  // EPI == 5
            float* C = (float*)C1;
            #pragma unroll
            for (int nt = 0; nt < 4; ++nt)
                #pragma unroll
                for (int r = 0; r < 4; ++r) {
                    const long rr = row0 + rb + r - (long)blockIdx.y * 1536;
                    C[rr * 512 + boff + nt * 16 + cb] = acc[nt][r];
                }
        }
    }
}

// ---------------------------------------------------------------------------
// Attention scores via MFMA, one block per hb = h*B+b.
// S[q,n] = (qv . k)/8 ; p = exp(S) (no max-sub: |S|<=8 after LN, p<=e^8<f16max);
// store p as f16 PAIR (split once here, so PV reads pairs directly) + lsum.
// ---------------------------------------------------------------------------
__global__ __launch_bounds__(256) void k_attn_mfma(
    const f16* __restrict__ qh, const f16* __restrict__ ql,
    const f16* __restrict__ kh, const f16* __restrict__ kl,
    f16* __restrict__ ath, f16* __restrict__ atl, float* __restrict__ lsum)
{
    __shared__ __align__(16) f16 Qh[64][72], Ql[64][72];
    __shared__ __align__(16) f16 Kh[64][72], Kl[64][72];

    const int t = threadIdx.x;
    const int hb = blockIdx.x;
    const int h = hb >> 3;
    const int L = t & 63, w = t >> 6;
    const int kq = (L >> 4) << 3;

    // stage Q (64 q-rows x 64 e)
    #pragma unroll
    for (int j = 0; j < 2; ++j) {
        const int i = t + j * 256;
        const int r = i >> 3, c8 = (i & 7) << 3;
        *(f16x8*)&Qh[r][c8] = *(const f16x8*)&qh[((long)h * 64 + r) * 64 + c8];
        *(f16x8*)&Ql[r][c8] = *(const f16x8*)&ql[((long)h * 64 + r) * 64 + c8];
    }
    __syncthreads();

    // persistent A-frags: wave w owns q-rows w*16..w*16+15
    f16x8 qah[2], qal[2];
    #pragma unroll
    for (int kc = 0; kc < 2; ++kc) {
        qah[kc] = *(const f16x8*)&Qh[w * 16 + (L & 15)][kc * 32 + kq];
        qal[kc] = *(const f16x8*)&Ql[w * 16 + (L & 15)][kc * 32 + kq];
    }

    float psum[4] = {0.f, 0.f, 0.f, 0.f};
    const int rowb = w * 16 + ((L >> 4) << 2);

    for (int n0 = 0; n0 < N; n0 += 64) {
        __syncthreads();
        #pragma unroll
        for (int j = 0; j < 2; ++j) {
            const int i = t + j * 256;
            const int r = i >> 3, c8 = (i & 7) << 3;
            *(f16x8*)&Kh[r][c8] = *(const f16x8*)&kh[((long)hb * N + n0 + r) * 64 + c8];
            *(f16x8*)&Kl[r][c8] = *(const f16x8*)&kl[((long)hb * N + n0 + r) * 64 + c8];
        }
        __syncthreads();

        floatx4 acc[4];
        #pragma unroll
        for (int nt = 0; nt < 4; ++nt)
            #pragma unroll
            for (int j = 0; j < 4; ++j) acc[nt][j] = 0.f;

        #pragma unroll
        for (int kc = 0; kc < 2; ++kc) {
            #pragma unroll
            for (int nt = 0; nt < 4; ++nt) {
                const f16x8 bh = *(const f16x8*)&Kh[nt * 16 + (L & 15)][kc * 32 + kq];
                const f16x8 bl = *(const f16x8*)&Kl[nt * 16 + (L & 15)][kc * 32 + kq];
                acc[nt] = __builtin_amdgcn_mfma_f32_16x16x32_f16(qah[kc], bh, acc[nt], 0, 0, 0);
                acc[nt] = __builtin_amdgcn_mfma_f32_16x16x32_f16(qah[kc], bl, acc[nt], 0, 0, 0);
                acc[nt] = __builtin_amdgcn_mfma_f32_16x16x32_f16(qal[kc], bh, acc[nt], 0, 0, 0);
            }
        }

        #pragma unroll
        for (int nt = 0; nt < 4; ++nt)
            #pragma unroll
            for (int r = 0; r < 4; ++r) {
                const float p = __expf(acc[nt][r] * 0.125f);
                psum[r] += p;
                f16 hh, ll; split(p, hh, ll);
                const long o = ((long)hb * 64 + rowb + r) * N + n0 + nt * 16 + (L & 15);
                ath[o] = hh; atl[o] = ll;
            }
    }

    // reduce row sums across the 16 lanes sharing each row
    #pragma unroll
    for (int r = 0; r < 4; ++r) {
        float s = psum[r];
        s += __shfl_xor(s, 1);
        s += __shfl_xor(s, 2);
        s += __shfl_xor(s, 4);
        s += __shfl_xor(s, 8);
        if ((L & 15) == 0) lsum[hb * 64 + rowb + r] = s;
    }
}

// ---------------------------------------------------------------------------
// PV1: U[hb*64+q, fd] = (1/lsum[row]) * sum_n p[row,n] * kv[b][n, fd]
// A = attn f16 pair; B = kv pair, K-major (stride 1536), transposed into LDS.
// Software-pipelined: next tile prefetched into regs during MFMA phase.
// Grid ct-major (same-(b,ct) blocks co-schedule -> kv from L2).
// ---------------------------------------------------------------------------
__global__ __launch_bounds__(256) void k_gemm3T(
    const f16* __restrict__ Ah, const f16* __restrict__ Al,
    const f16* __restrict__ Bh, const f16* __restrict__ Bl,
    const float* __restrict__ lsum,
    f16* __restrict__ Uh, f16* __restrict__ Ul)
{
    __shared__ __align__(16) f16 Ash[64][72];
    __shared__ __align__(16) f16 Asl[64][72];
    __shared__ __align__(16) f16 Bsh[64][72];
    __shared__ __align__(16) f16 Bsl[64][72];

    const int t = threadIdx.x;
    const int by = blockIdx.x;
    const int hb = by & 63, ct = by >> 6;   // ct-major grid for L2 kv reuse
    const int b = hb & 7;
    const f16* Abh = Ah + (long)hb * 64 * 2048;
    const f16* Abl = Al + (long)hb * 64 * 2048;
    const f16* Bbh = Bh + (long)b * 2048 * 1536 + ct * 64;
    const f16* Bbl = Bl + (long)b * 2048 * 1536 + ct * 64;

    floatx4 acc[4];
    #pragma unroll
    for (int nt = 0; nt < 4; ++nt)
        #pragma unroll
        for (int j = 0; j < 4; ++j) acc[nt][j] = 0.f;

    const int L = t & 63, w = t >> 6;
    const int kq = (L >> 4) << 3;
    const int ar = t >> 3, ac = (t & 7) << 3;    // A map: conflict-free stores
    const int k2 = t & 31, c8 = (t >> 5) << 3;   // B-transpose map: 2-way banks

    f16x8 pA0, pA1, pA2, pA3, pB0, pB1, pB2, pB3;
    {
        pA0 = *(const f16x8*)&Abh[(long)ar * 2048 + ac];
        pA1 = *(const f16x8*)&Abh[(long)(ar + 32) * 2048 + ac];
        pA2 = *(const f16x8*)&Abl[(long)ar * 2048 + ac];
        pA3 = *(const f16x8*)&Abl[(long)(ar + 32) * 2048 + ac];
        pB0 = *(const f16x8*)&Bbh[(long)(2 * k2) * 1536 + c8];
        pB1 = *(const f16x8*)&Bbh[(long)(2 * k2 + 1) * 1536 + c8];
        pB2 = *(const f16x8*)&Bbl[(long)(2 * k2) * 1536 + c8];
        pB3 = *(const f16x8*)&Bbl[(long)(2 * k2 + 1) * 1536 + c8];
    }

    for (int k0 = 0; k0 < 2048; k0 += 64) {
        // store prefetched tile to LDS
        *(f16x8*)&Ash[ar][ac]      = pA0;
        *(f16x8*)&Ash[ar + 32][ac] = pA1;
        *(f16x8*)&Asl[ar][ac]      = pA2;
        *(f16x8*)&Asl[ar + 32][ac] = pA3;
        #pragma unroll
        for (int j = 0; j < 8; ++j) {
            f16x2 ph; ph[0] = pB0[j]; ph[1] = pB1[j];
            f16x2 pl; pl[0] = pB2[j]; pl[1] = pB3[j];
            *(f16x2*)&Bsh[c8 + j][2 * k2] = ph;
            *(f16x2*)&Bsl[c8 + j][2 * k2] = pl;
        }
        __syncthreads();

        // prefetch next tile (overlaps with MFMA below)
        if (k0 + 64 < 2048) {
            const int kn = k0 + 64;
            pA0 = *(const f16x8*)&Abh[(long)ar * 2048 + kn + ac];
            pA1 = *(const f16x8*)&Abh[(long)(ar + 32) * 2048 + kn + ac];
            pA2 = *(const f16x8*)&Abl[(long)ar * 2048 + kn + ac];
            pA3 = *(const f16x8*)&Abl[(long)(ar + 32) * 2048 + kn + ac];
            pB0 = *(const f16x8*)&Bbh[(long)(kn + 2 * k2) * 1536 + c8];
            pB1 = *(const f16x8*)&Bbh[(long)(kn + 2 * k2 + 1) * 1536 + c8];
            pB2 = *(const f16x8*)&Bbl[(long)(kn + 2 * k2) * 1536 + c8];
            pB3 = *(const f16x8*)&Bbl[(long)(kn + 2 * k2 + 1) * 1536 + c8];
        }

        #pragma unroll
        for (int kk = 0; kk < 64; kk += 32) {
            const f16x8 ah0 = *(const f16x8*)&Ash[w * 16 + (L & 15)][kk + kq];
            const f16x8 al0 = *(const f16x8*)&Asl[w * 16 + (L & 15)][kk + kq];
            #pragma unroll
            for (int nt = 0; nt < 4; ++nt) {
                const f16x8 bh = *(const f16x8*)&Bsh[nt * 16 + (L & 15)][kk + kq];
                const f16x8 bl = *(const f16x8*)&Bsl[nt * 16 + (L & 15)][kk + kq];
                acc[nt] = __builtin_amdgcn_mfma_f32_16x16x32_f16(ah0, bh, acc[nt], 0, 0, 0);
                acc[nt] = __builtin_amdgcn_mfma_f32_16x16x32_f16(ah0, bl, acc[nt], 0, 0, 0);
                acc[nt] = __builtin_amdgcn_mfma_f32_16x16x32_f16(al0, bh, acc[nt], 0, 0, 0);
            }
        }
        __syncthreads();
    }

    const int cb = L & 15;
    const int rb = w * 16 + ((L >> 4) << 2);
    #pragma unroll
    for (int r = 0; r < 4; ++r) {
        const float inv = 1.f / lsum[hb * 64 + rb + r];
        #pragma unroll
        for (int nt = 0; nt < 4; ++nt) {
            f16 h, l; split(acc[nt][r] * inv, h, l);
            const long o = ((long)hb * 64 + rb + r) * 1536 + ct * 64 + nt * 16 + cb;
            Uh[o] = h; Ul[o] = l;
        }
    }
}

// ---------------------------------------------------------------------------
// f32 [K,N] -> transposed f16 pair [N,K]
__global__ void k_castTpair(const float* __restrict__ s, f16* __restrict__ dh,
                            f16* __restrict__ dl, int K, int Nn)
{
    const long i = (long)blockIdx.x * 256 + threadIdx.x;
    if (i >= (long)K * Nn) return;
    const int k = (int)(i / Nn), n = (int)(i - (long)k * Nn);
    f16 h, l; split(s[i], h, l);
    dh[(long)n * K + k] = h;
    dl[(long)n * K + k] = l;
}

// normb pair = f16pair( sqrt(sum_f kv_pre^2) + EPS ), one thread per (tk,c)
__global__ void k_norm(const f16* __restrict__ kh, const f16* __restrict__ kl,
                       f16* __restrict__ nh, f16* __restrict__ nl)
{
    const long i = (long)blockIdx.x * 256 + threadIdx.x;
    const int tk = (int)(i >> 9), c = (int)(i & 511);
    const long base = (long)tk * 1536 + c;
    const float a = (float)kh[base]        + (float)kl[base];
    const float b = (float)kh[base + 512]  + (float)kl[base + 512];
    const float cc = (float)kh[base + 1024] + (float)kl[base + 1024];
    f16 h, l; split(sqrtf(a * a + b * b + cc * cc) + EPS, h, l);
    nh[i] = h; nl[i] = l;
}

// gate (in-place on kv pair) + kinv pair. One block per token.
__global__ __launch_bounds__(256) void k_gate(
    f16* __restrict__ kh, f16* __restrict__ kl, const float* __restrict__ g,
    f16* __restrict__ kih, f16* __restrict__ kil)
{
    __shared__ float red[3][4];
    const int t = threadIdx.x;
    const int tk = blockIdx.x;
    float kv[2][3];
    float ps0 = 0.f, ps1 = 0.f, ps2 = 0.f;
    #pragma unroll
    for (int j = 0; j < 2; ++j) {
        const int c = t + j * 256;
        const long base = (long)tk * 1536 + c;
        const float k0 = (float)kh[base]        + (float)kl[base];
        const float k1 = (float)kh[base + 512]  + (float)kl[base + 512];
        const float k2 = (float)kh[base + 1024] + (float)kl[base + 1024];
        const float nr = sqrtf(k0 * k0 + k1 * k1 + k2 * k2);
        const float gv = g[(long)tk * 512 + c];
        const float s = (nr <= EPS) ? 1.f : gv / (nr + EPS);
        kv[j][0] = k0 * s; kv[j][1] = k1 * s; kv[j][2] = k2 * s;
        f16 h, l;
        split(kv[j][0], h, l); kh[base] = h;        kl[base] = l;
        split(kv[j][1], h, l); kh[base + 512] = h;  kl[base + 512] = l;
        split(kv[j][2], h, l); kh[base + 1024] = h; kl[base + 1024] = l;
        ps0 += kv[j][0]; ps1 += kv[j][1]; ps2 += kv[j][2];
    }
    for (int off = 32; off; off >>= 1) {
        ps0 += __shfl_down(ps0, off);
        ps1 += __shfl_down(ps1, off);
        ps2 += __shfl_down(ps2, off);
    }
    if ((t & 63) == 0) { red[0][t >> 6] = ps0; red[1][t >> 6] = ps1; red[2][t >> 6] = ps2; }
    __syncthreads();
    const float m0 = (red[0][0] + red[0][1] + red[0][2] + red[0][3]) * (1.f / 512.f);
    const float m1 = (red[1][0] + red[1][1] + red[1][2] + red[1][3]) * (1.f / 512.f);
    const float m2 = (red[2][0] + red[2][1] + red[2][2] + red[2][3]) * (1.f / 512.f);
    #pragma unroll
    for (int j = 0; j < 2; ++j) {
        const int c = t + j * 256;
        f16 h, l; split(kv[j][0] * m0 + kv[j][1] * m1 + kv[j][2] * m2, h, l);
        kih[(long)tk * 512 + c] = h;
        kil[(long)tk * 512 + c] = l;
    }
}

// ---------------------------------------------------------------------------
// q = LN(lq @ wq) per head (fp32 VALU, tiny), output f16 pair [h][qi][64].
__global__ __launch_bounds__(256) void k_qproj(
    const float* __restrict__ lq, const float* __restrict__ wq,
    const float* __restrict__ lns, const float* __restrict__ lnb,
    f16* __restrict__ qh, f16* __restrict__ ql)
{
    __shared__ float cs[QK];
    const int t = threadIdx.x;
    const int qi = blockIdx.x;
    const float* cp = lq + (long)qi * QK;
    for (int i = t; i < QK; i += 256) cs[i] = cp[i];
    __syncthreads();

    float a0 = 0, a1 = 0;
    #pragma unroll 4
    for (int d = 0; d < QK; ++d) {
        const float c = cs[d];
        a0 += c * wq[d * QK + t];
        a1 += c * wq[d * QK + t + 256];
    }
    float s0 = a0, q0 = a0 * a0, s1 = a1, q1 = a1 * a1;
    for (int off = 32; off; off >>= 1) {
        s0 += __shfl_down(s0, off); q0 += __shfl_down(q0, off);
        s1 += __shfl_down(s1, off); q1 += __shfl_down(q1, off);
    }
    s0 = __shfl(s0, 0); q0 = __shfl(q0, 0);
    s1 = __shfl(s1, 0); q1 = __shfl(q1, 0);
    const float mean0 = s0 * (1.f / 64.f), var0 = q0 * (1.f / 64.f) - mean0 * mean0;
    const float mean1 = s1 * (1.f / 64.f), var1 = q1 * (1.f / 64.f) - mean1 * mean1;
    const int e = t & 63;
    const float sc = lns[e], bi = lnb[e];
    const float r0 = (a0 - mean0) * rsqrtf(var0 + LNE) * sc + bi;
    const float r1 = (a1 - mean1) * rsqrtf(var1 + LNE) * sc + bi;
    const int h0 = t >> 6, h1 = h0 + 4;
    f16 h, l;
    split(r0, h, l);
    qh[((long)h0 * Qq + qi) * DH + e] = h;
    ql[((long)h0 * Qq + qi) * DH + e] = l;
    split(r1, h, l);
    qh[((long)h1 * Qq + qi) * DH + e] = h;
    ql[((long)h1 * Qq + qi) * DH + e] = l;
}

// ---------------------------------------------------------------------------
// out = EVN2(resiT @ w_out), fp32 store. One block per (b,q).
__global__ __launch_bounds__(256) void k_out(
    const float* __restrict__ resiT, const float* __restrict__ w_out,
    const float* __restrict__ w2a, const float* __restrict__ b2a,
    const float* __restrict__ w2b, const float* __restrict__ b2b,
    float* __restrict__ out)
{
    __shared__ float rs[Fv * Vd];
    __shared__ float norm_s[Vd];
    __shared__ float h_s[256];

    const int t = threadIdx.x;
    const long bq = blockIdx.x;
    const float* rp = resiT + bq * (Fv * Vd);
    for (int i = t; i < Fv * Vd; i += 256) rs[i] = rp[i];
    __syncthreads();

    float a0 = 0, a1 = 0, a2 = 0, a3 = 0, a4 = 0, a5 = 0;
    #pragma unroll 4
    for (int d = 0; d < Vd; ++d) {
        const float w0 = w_out[d * Vd + t];
        const float w1 = w_out[d * Vd + t + 256];
        const float x0 = rs[d], x1 = rs[Vd + d], x2 = rs[2 * Vd + d];
        a0 += x0 * w0; a1 += x1 * w0; a2 += x2 * w0;
        a3 += x0 * w1; a4 += x1 * w1; a5 += x2 * w1;
    }
    const float nrm0 = sqrtf(a0 * a0 + a1 * a1 + a2 * a2);
    const float nrm1 = sqrtf(a3 * a3 + a4 * a4 + a5 * a5);
    norm_s[t] = nrm0;
    norm_s[t + 256] = nrm1;
    __syncthreads();

    float hacc = b2a[t];
    #pragma unroll 4
    for (int d = 0; d < Vd; ++d) hacc += (norm_s[d] + EPS) * w2a[d * 256 + t];
    h_s[t] = hacc > 0.f ? hacc : NEG * hacc;
    __syncthreads();

    float g0 = b2b[t], g1 = b2b[t + 256];
    #pragma unroll 4
    for (int j = 0; j < 256; ++j) {
        const float hv = h_s[j];
        g0 += hv * w2b[j * Vd + t];
        g1 += hv * w2b[j * Vd + t + 256];
    }
    const float s0 = (nrm0 <= EPS) ? 1.f : g0 / (nrm0 + EPS);
    const float s1 = (nrm1 <= EPS) ? 1.f : g1 / (nrm1 + EPS);

    float* op = out + bq * (Fv * Vd);
    op[0 * Vd + t]       = a0 * s0;
    op[1 * Vd + t]       = a1 * s0;
    op[2 * Vd + t]       = a2 * s0;
    op[0 * Vd + t + 256] = a3 * s1;
    op[1 * Vd + t + 256] = a4 * s1;
    op[2 * Vd + t + 256] = a5 * s1;
}

// ---------------------------------------------------------------------------
extern "C" void kernel_launch(void* const* d_in, const int* in_sizes, int n_in,
                              void* d_out, int out_size, void* d_ws, size_t ws_size,
                              hipStream_t stream)
{
    const float* x    = (const float*)d_in[0];
    const float* lq   = (const float*)d_in[1];
    const float* w_kv = (const float*)d_in[2];
    const float* w1a  = (const float*)d_in[3];
    const float* b1a  = (const float*)d_in[4];
    const float* w1b  = (const float*)d_in[5];
    const float* b1b  = (const float*)d_in[6];
    const float* wq   = (const float*)d_in[7];
    const float* wk   = (const float*)d_in[8];
    const float* wv   = (const float*)d_in[9];
    const float* lqs  = (const float*)d_in[10];
    const float* lqb  = (const float*)d_in[11];
    const float* lks  = (const float*)d_in[12];
    const float* lkb  = (const float*)d_in[13];
    const float* wo   = (const float*)d_in[14];
    const float* w2a  = (const float*)d_in[15];
    const float* b2a  = (const float*)d_in[16];
    const float* w2b  = (const float*)d_in[17];
    const float* b2b  = (const float*)d_in[18];

    char* ws = (char*)d_ws;
    // Layout (191.5 MB, lifetime-aliased):
    //  W  [0, 3670016): weight pairs
    //  S  [3670016, 3817472): qhp 64K | qlp 64K | lsum 16K
    //  A1 [6946816, 40501248): normb pair -> kinv pair -> attn f16 pair
    //  A2 [40501248, 57278464): hb pair -> resiT f32 (hb dead after step 5)
    //  B  [57278464, 157941760): kv pair (pre -> gated in-place)
    //  D  [157941760, 191496192): g f32 -> k pair -> U pair
    f16* wkvTh = (f16*)(ws + 0);
    f16* wkvTl = (f16*)(ws + 262144);
    f16* w1aTh = (f16*)(ws + 524288);
    f16* w1aTl = (f16*)(ws + 786432);
    f16* w1bTh = (f16*)(ws + 1048576);
    f16* w1bTl = (f16*)(ws + 1310720);
    f16* wkTh  = (f16*)(ws + 1572864);
    f16* wkTl  = (f16*)(ws + 2097152);
    f16* wvTh  = (f16*)(ws + 2621440);
    f16* wvTl  = (f16*)(ws + 3145728);
    f16*   qhp   = (f16*)(ws + 3670016);   // 65536 B
    f16*   qlp   = (f16*)(ws + 3735552);   // 65536 B
    float* lsum  = (float*)(ws + 3801088); // 16384 B
    f16* nh    = (f16*)(ws + 6946816);
    f16* nl    = (f16*)(ws + 23724032);
    f16* kih   = nh;
    f16* kil   = nl;
    f16* ath   = (f16*)(ws + 6946816);     // attn pair aliases normb/kinv
    f16* atl   = (f16*)(ws + 23724032);
    f16* hbh   = (f16*)(ws + 40501248);
    f16* hbl   = (f16*)(ws + 48889856);
    float* resiT = (float*)(ws + 40501248); // aliases hb (dead after step 5)
    f16* kvh   = (f16*)(ws + 57278464);
    f16* kvl   = (f16*)(ws + 107610112);
    float* g    = (float*)(ws + 157941760);
    f16* khb   = (f16*)(ws + 157941760);
    f16* klb   = (f16*)(ws + 174718976);
    f16* Uh    = (f16*)(ws + 157941760);
    f16* Ul    = (f16*)(ws + 170524672);
    float* out  = (float*)d_out;

    // 1. weight casts (transposed pairs)
    k_castTpair<<<512,  256, 0, stream>>>(w_kv, wkvTh, wkvTl, Dd, QK);
    k_castTpair<<<512,  256, 0, stream>>>(w1a,  w1aTh, w1aTl, QK, 256);
    k_castTpair<<<512,  256, 0, stream>>>(w1b,  w1bTh, w1bTl, 256, QK);
    k_castTpair<<<1024, 256, 0, stream>>>(wk,   wkTh,  wkTl,  QK, QK);
    k_castTpair<<<1024, 256, 0, stream>>>(wv,   wvTh,  wvTl,  QK, QK);

    // 2. kv_pre = x @ w_kv   (A = fp32 x, split on the fly) -> kv pair
    k_gemm3<1, 0><<<dim3(384, 8), 256, 0, stream>>>(
        x, nullptr, nullptr, wkvTh, wkvTl, QK, Dd, kvh, kvl, nullptr, nullptr);
    // 3. norm
    k_norm<<<32768, 256, 0, stream>>>(kvh, kvl, nh, nl);
    // 4. h = leaky(norm @ w1a + b1a) -> hb pair
    k_gemm3<0, 1><<<dim3(128, 4), 256, 0, stream>>>(
        nullptr, nh, nl, w1aTh, w1aTl, 256, QK, hbh, hbl, b1a, nullptr);
    // 5. g = h @ w1b + b1b -> f32
    k_gemm3<0, 2><<<dim3(128, 8), 256, 0, stream>>>(
        nullptr, hbh, hbl, w1bTh, w1bTl, QK, 256, g, nullptr, b1b, nullptr);
    // 6. gate in-place + kinv pair
    k_gate<<<NT, 256, 0, stream>>>(kvh, kvl, g, kih, kil);
    // 7. k = LN(kinv @ wk) -> k pair [h][tok][64]
    k_gemm3<0, 3><<<dim3(128, 8), 256, 0, stream>>>(
        nullptr, kih, kil, wkTh, wkTl, QK, QK, khb, klb, lks, lkb);
    // 8. q -> pair
    k_qproj<<<Qq, 256, 0, stream>>>(lq, wq, lqs, lqb, qhp, qlp);
    // 9. attn: MFMA QK^T + exp + rowsum -> f16 pair (unnormalized)
    k_attn_mfma<<<Hh * B, 256, 0, stream>>>(qhp, qlp, khb, klb, ath, atl, lsum);
    // 10. U = (attn @ kv) / lsum -> U pair   (pipelined)
    k_gemm3T<<<64 * 24, 256, 0, stream>>>(ath, atl, kvh, kvl, lsum, Uh, Ul);
    // 11. resi = U @ wv -> resiT f32
    k_gemm3<0, 5><<<dim3(12, 8), 256, 0, stream>>>(
        nullptr, Uh, Ul, wvTh, wvTl, 64, QK, resiT, nullptr, nullptr, nullptr);
    // 12. out
    k_out<<<B * Qq, 256, 0, stream>>>(resiT, wo, w2a, b2a, w2b, b2b, out);
}

// Round 11
// 643.956 us; speedup vs baseline: 2.8525x; 1.1421x over previous
//
#include <hip/hip_runtime.h>
#include <hip/hip_bf16.h>

typedef _Float16 f16;
typedef __attribute__((ext_vector_type(8))) _Float16 f16x8;
typedef __attribute__((ext_vector_type(4))) _Float16 f16x4;
typedef __attribute__((ext_vector_type(2))) _Float16 f16x2;
typedef __attribute__((ext_vector_type(4))) float floatx4;

// Problem constants
constexpr int B  = 8;
constexpr int N  = 2048;
constexpr int Fv = 3;
constexpr int Dd = 256;
constexpr int QK = 512;
constexpr int Vd = 512;
constexpr int Hh = 8;
constexpr int Qq = 64;
constexpr int DH = 64;
constexpr int NT = B * N;          // 16384 tokens
constexpr float EPS = 1e-6f;
constexpr float NEG = 0.2f;
constexpr float LNE = 1e-6f;

#define DEV static __device__ __forceinline__
DEV void split(float v, f16& h, f16& l) { h = (f16)v; l = (f16)(v - (float)h); }

// ---------------------------------------------------------------------------
// Split-fp16 3-mul GEMM (effective fp32 accuracy): C = A[M,K] @ B[K,N]
// A as (Ah,Al) f16 pairs (ASRC=0) or fp32 split on the fly (ASRC=1).
// Bt = B^T row-major [N,K] as (Bh,Bl) pairs.
// Block 256 thr = 4 waves; tile 128M x 64N; wave = 32 rows x 64 cols.
// EPI: 0 pair store                 1 +bias,leaky -> pair
//      2 +bias -> f32               3 per-64col LN -> f16 pair [h][tok][64]
//      5 PV2: store f32 resiT[(b,q,f)][512] at col h*64+
// ---------------------------------------------------------------------------
template<int ASRC, int EPI>
__global__ __launch_bounds__(256) void k_gemm3(
    const float* __restrict__ A32,
    const f16* __restrict__ Ah, const f16* __restrict__ Al,
    const f16* __restrict__ Bh, const f16* __restrict__ Bl,
    int Ndim, int Kdim, void* __restrict__ C1, void* __restrict__ C2,
    const float* __restrict__ e0, const float* __restrict__ e1)
{
    __shared__ __align__(16) f16 Ash[128][72];
    __shared__ __align__(16) f16 Asl[128][72];
    __shared__ __align__(16) f16 Bsh[64][72];
    __shared__ __align__(16) f16 Bsl[64][72];

    const int t = threadIdx.x;
    long row0; int col0, boff;
    if (EPI == 5) { row0 = (long)blockIdx.y * 1536 + (long)blockIdx.x * 128; col0 = 0; boff = blockIdx.y * 64; }
    else          { row0 = (long)blockIdx.x * 128; col0 = blockIdx.y * 64; boff = 0; }

    floatx4 acc0[4], acc1[4];
    #pragma unroll
    for (int nt = 0; nt < 4; ++nt)
        #pragma unroll
        for (int j = 0; j < 4; ++j) { acc0[nt][j] = 0.f; acc1[nt][j] = 0.f; }

    const int L = t & 63, w = t >> 6;
    const int kq = (L >> 4) << 3;

    for (int k0 = 0; k0 < Kdim; k0 += 64) {
        if constexpr (ASRC == 1) {
            #pragma unroll
            for (int j = 0; j < 8; ++j) {
                const int i = t + j * 256;
                const int r = i >> 4, c4 = (i & 15) << 2;
                const floatx4 v = *(const floatx4*)&A32[(row0 + r) * Kdim + k0 + c4];
                f16x4 h4, l4;
                #pragma unroll
                for (int m = 0; m < 4; ++m) { h4[m] = (f16)v[m]; l4[m] = (f16)(v[m] - (float)h4[m]); }
                *(f16x4*)&Ash[r][c4] = h4;
                *(f16x4*)&Asl[r][c4] = l4;
            }
        } else {
            #pragma unroll
            for (int j = 0; j < 4; ++j) {
                const int i = t + j * 256;
                const int r = i >> 3, c8 = (i & 7) << 3;
                *(f16x8*)&Ash[r][c8] = *(const f16x8*)&Ah[(row0 + r) * (long)Kdim + k0 + c8];
                *(f16x8*)&Asl[r][c8] = *(const f16x8*)&Al[(row0 + r) * (long)Kdim + k0 + c8];
            }
        }
        #pragma unroll
        for (int j = 0; j < 2; ++j) {
            const int i = t + j * 256;
            const int r = i >> 3, c8 = (i & 7) << 3;
            *(f16x8*)&Bsh[r][c8] = *(const f16x8*)&Bh[(long)(boff + col0 + r) * Kdim + k0 + c8];
            *(f16x8*)&Bsl[r][c8] = *(const f16x8*)&Bl[(long)(boff + col0 + r) * Kdim + k0 + c8];
        }
        __syncthreads();
        #pragma unroll
        for (int kk = 0; kk < 64; kk += 32) {
            const f16x8 ah0 = *(const f16x8*)&Ash[w * 32 + (L & 15)][kk + kq];
            const f16x8 al0 = *(const f16x8*)&Asl[w * 32 + (L & 15)][kk + kq];
            const f16x8 ah1 = *(const f16x8*)&Ash[w * 32 + 16 + (L & 15)][kk + kq];
            const f16x8 al1 = *(const f16x8*)&Asl[w * 32 + 16 + (L & 15)][kk + kq];
            #pragma unroll
            for (int nt = 0; nt < 4; ++nt) {
                const f16x8 bh = *(const f16x8*)&Bsh[nt * 16 + (L & 15)][kk + kq];
                const f16x8 bl = *(const f16x8*)&Bsl[nt * 16 + (L & 15)][kk + kq];
                acc0[nt] = __builtin_amdgcn_mfma_f32_16x16x32_f16(ah0, bh, acc0[nt], 0, 0, 0);
                acc0[nt] = __builtin_amdgcn_mfma_f32_16x16x32_f16(ah0, bl, acc0[nt], 0, 0, 0);
                acc0[nt] = __builtin_amdgcn_mfma_f32_16x16x32_f16(al0, bh, acc0[nt], 0, 0, 0);
                acc1[nt] = __builtin_amdgcn_mfma_f32_16x16x32_f16(ah1, bh, acc1[nt], 0, 0, 0);
                acc1[nt] = __builtin_amdgcn_mfma_f32_16x16x32_f16(ah1, bl, acc1[nt], 0, 0, 0);
                acc1[nt] = __builtin_amdgcn_mfma_f32_16x16x32_f16(al1, bh, acc1[nt], 0, 0, 0);
            }
        }
        __syncthreads();
    }

    // C/D layout: col = lane&15, row = (lane>>4)*4 + reg
    const int cb = L & 15;
    #pragma unroll
    for (int rt = 0; rt < 2; ++rt) {
        const floatx4* acc = rt ? acc1 : acc0;
        const int rb = w * 32 + rt * 16 + ((L >> 4) << 2);
        if constexpr (EPI == 0) {
            f16* Ch = (f16*)C1; f16* Cl = (f16*)C2;
            #pragma unroll
            for (int nt = 0; nt < 4; ++nt)
                #pragma unroll
                for (int r = 0; r < 4; ++r) {
                    f16 h, l; split(acc[nt][r], h, l);
                    const long o = (row0 + rb + r) * (long)Ndim + col0 + nt * 16 + cb;
                    Ch[o] = h; Cl[o] = l;
                }
        } else if constexpr (EPI == 1) {
            f16* Ch = (f16*)C1; f16* Cl = (f16*)C2;
            #pragma unroll
            for (int nt = 0; nt < 4; ++nt) {
                const int col = col0 + nt * 16 + cb;
                const float bias = e0[col];
                #pragma unroll
                for (int r = 0; r < 4; ++r) {
                    float v = acc[nt][r] + bias;
                    v = v > 0.f ? v : NEG * v;
                    f16 h, l; split(v, h, l);
                    const long o = (row0 + rb + r) * (long)Ndim + col;
                    Ch[o] = h; Cl[o] = l;
                }
            }
        } else if constexpr (EPI == 2) {
            float* C = (float*)C1;
            #pragma unroll
            for (int nt = 0; nt < 4; ++nt) {
                const int col = col0 + nt * 16 + cb;
                const float bias = e0[col];
                #pragma unroll
                for (int r = 0; r < 4; ++r)
                    C[(row0 + rb + r) * (long)Ndim + col] = acc[nt][r] + bias;
            }
        } else if constexpr (EPI == 3) {
            f16* Ch = (f16*)C1; f16* Cl = (f16*)C2;
            const int h = blockIdx.y;
            #pragma unroll
            for (int r = 0; r < 4; ++r) {
                float s = 0.f, q = 0.f;
                #pragma unroll
                for (int nt = 0; nt < 4; ++nt) { const float v = acc[nt][r]; s += v; q += v * v; }
                s += __shfl_xor(s, 1); q += __shfl_xor(q, 1);
                s += __shfl_xor(s, 2); q += __shfl_xor(q, 2);
                s += __shfl_xor(s, 4); q += __shfl_xor(q, 4);
                s += __shfl_xor(s, 8); q += __shfl_xor(q, 8);
                const float mean = s * (1.f / 64.f);
                const float var  = q * (1.f / 64.f) - mean * mean;
                const float rs   = rsqrtf(var + LNE);
                #pragma unroll
                for (int nt = 0; nt < 4; ++nt) {
                    const int col = nt * 16 + cb;
                    const float v = (acc[nt][r] - mean) * rs * e0[col] + e1[col];
                    f16 hh, ll; split(v, hh, ll);
                    const long o = ((long)h * NT + row0 + rb + r) * 64 + col;
                    Ch[o] = hh; Cl[o] = ll;
                }
            }
        } else {  // EPI == 5
            float* C = (float*)C1;
            #pragma unroll
            for (int nt = 0; nt < 4; ++nt)
                #pragma unroll
                for (int r = 0; r < 4; ++r) {
                    const long rr = row0 + rb + r - (long)blockIdx.y * 1536;
                    C[rr * 512 + boff + nt * 16 + cb] = acc[nt][r];
                }
        }
    }
}

// ---------------------------------------------------------------------------
// Attention scores via MFMA, one block per hb = h*B+b.
// S[q,n] = (qv . k)/8 ; p = exp(S) (no max-sub: |S|<=8 after LN, p<=e^8<f16max);
// store p as f16 PAIR + lsum. Normalization folded into PV.
// ---------------------------------------------------------------------------
__global__ __launch_bounds__(256) void k_attn_mfma(
    const f16* __restrict__ qh, const f16* __restrict__ ql,
    const f16* __restrict__ kh, const f16* __restrict__ kl,
    f16* __restrict__ ath, f16* __restrict__ atl, float* __restrict__ lsum)
{
    __shared__ __align__(16) f16 Qh[64][72], Ql[64][72];
    __shared__ __align__(16) f16 Kh[64][72], Kl[64][72];

    const int t = threadIdx.x;
    const int hb = blockIdx.x;
    const int h = hb >> 3;
    const int L = t & 63, w = t >> 6;
    const int kq = (L >> 4) << 3;

    #pragma unroll
    for (int j = 0; j < 2; ++j) {
        const int i = t + j * 256;
        const int r = i >> 3, c8 = (i & 7) << 3;
        *(f16x8*)&Qh[r][c8] = *(const f16x8*)&qh[((long)h * 64 + r) * 64 + c8];
        *(f16x8*)&Ql[r][c8] = *(const f16x8*)&ql[((long)h * 64 + r) * 64 + c8];
    }
    __syncthreads();

    f16x8 qah[2], qal[2];
    #pragma unroll
    for (int kc = 0; kc < 2; ++kc) {
        qah[kc] = *(const f16x8*)&Qh[w * 16 + (L & 15)][kc * 32 + kq];
        qal[kc] = *(const f16x8*)&Ql[w * 16 + (L & 15)][kc * 32 + kq];
    }

    float psum[4] = {0.f, 0.f, 0.f, 0.f};
    const int rowb = w * 16 + ((L >> 4) << 2);

    for (int n0 = 0; n0 < N; n0 += 64) {
        __syncthreads();
        #pragma unroll
        for (int j = 0; j < 2; ++j) {
            const int i = t + j * 256;
            const int r = i >> 3, c8 = (i & 7) << 3;
            *(f16x8*)&Kh[r][c8] = *(const f16x8*)&kh[((long)hb * N + n0 + r) * 64 + c8];
            *(f16x8*)&Kl[r][c8] = *(const f16x8*)&kl[((long)hb * N + n0 + r) * 64 + c8];
        }
        __syncthreads();

        floatx4 acc[4];
        #pragma unroll
        for (int nt = 0; nt < 4; ++nt)
            #pragma unroll
            for (int j = 0; j < 4; ++j) acc[nt][j] = 0.f;

        #pragma unroll
        for (int kc = 0; kc < 2; ++kc) {
            #pragma unroll
            for (int nt = 0; nt < 4; ++nt) {
                const f16x8 bh = *(const f16x8*)&Kh[nt * 16 + (L & 15)][kc * 32 + kq];
                const f16x8 bl = *(const f16x8*)&Kl[nt * 16 + (L & 15)][kc * 32 + kq];
                acc[nt] = __builtin_amdgcn_mfma_f32_16x16x32_f16(qah[kc], bh, acc[nt], 0, 0, 0);
                acc[nt] = __builtin_amdgcn_mfma_f32_16x16x32_f16(qah[kc], bl, acc[nt], 0, 0, 0);
                acc[nt] = __builtin_amdgcn_mfma_f32_16x16x32_f16(qal[kc], bh, acc[nt], 0, 0, 0);
            }
        }

        #pragma unroll
        for (int nt = 0; nt < 4; ++nt)
            #pragma unroll
            for (int r = 0; r < 4; ++r) {
                const float p = __expf(acc[nt][r] * 0.125f);
                psum[r] += p;
                f16 hh, ll; split(p, hh, ll);
                const long o = ((long)hb * 64 + rowb + r) * N + n0 + nt * 16 + (L & 15);
                ath[o] = hh; atl[o] = ll;
            }
    }

    #pragma unroll
    for (int r = 0; r < 4; ++r) {
        float s = psum[r];
        s += __shfl_xor(s, 1);
        s += __shfl_xor(s, 2);
        s += __shfl_xor(s, 4);
        s += __shfl_xor(s, 8);
        if ((L & 15) == 0) lsum[hb * 64 + rowb + r] = s;
    }
}

// ---------------------------------------------------------------------------
// PV1: U[hb*64+q, fd] = (1/lsum[row]) * sum_n p[row,n] * kv[b][n, fd]
// Software-pipelined; ct-major grid for L2 kv reuse.
// ---------------------------------------------------------------------------
__global__ __launch_bounds__(256) void k_gemm3T(
    const f16* __restrict__ Ah, const f16* __restrict__ Al,
    const f16* __restrict__ Bh, const f16* __restrict__ Bl,
    const float* __restrict__ lsum,
    f16* __restrict__ Uh, f16* __restrict__ Ul)
{
    __shared__ __align__(16) f16 Ash[64][72];
    __shared__ __align__(16) f16 Asl[64][72];
    __shared__ __align__(16) f16 Bsh[64][72];
    __shared__ __align__(16) f16 Bsl[64][72];

    const int t = threadIdx.x;
    const int by = blockIdx.x;
    const int hb = by & 63, ct = by >> 6;
    const int b = hb & 7;
    const f16* Abh = Ah + (long)hb * 64 * 2048;
    const f16* Abl = Al + (long)hb * 64 * 2048;
    const f16* Bbh = Bh + (long)b * 2048 * 1536 + ct * 64;
    const f16* Bbl = Bl + (long)b * 2048 * 1536 + ct * 64;

    floatx4 acc[4];
    #pragma unroll
    for (int nt = 0; nt < 4; ++nt)
        #pragma unroll
        for (int j = 0; j < 4; ++j) acc[nt][j] = 0.f;

    const int L = t & 63, w = t >> 6;
    const int kq = (L >> 4) << 3;
    const int ar = t >> 3, ac = (t & 7) << 3;
    const int k2 = t & 31, c8 = (t >> 5) << 3;

    f16x8 pA0, pA1, pA2, pA3, pB0, pB1, pB2, pB3;
    {
        pA0 = *(const f16x8*)&Abh[(long)ar * 2048 + ac];
        pA1 = *(const f16x8*)&Abh[(long)(ar + 32) * 2048 + ac];
        pA2 = *(const f16x8*)&Abl[(long)ar * 2048 + ac];
        pA3 = *(const f16x8*)&Abl[(long)(ar + 32) * 2048 + ac];
        pB0 = *(const f16x8*)&Bbh[(long)(2 * k2) * 1536 + c8];
        pB1 = *(const f16x8*)&Bbh[(long)(2 * k2 + 1) * 1536 + c8];
        pB2 = *(const f16x8*)&Bbl[(long)(2 * k2) * 1536 + c8];
        pB3 = *(const f16x8*)&Bbl[(long)(2 * k2 + 1) * 1536 + c8];
    }

    for (int k0 = 0; k0 < 2048; k0 += 64) {
        *(f16x8*)&Ash[ar][ac]      = pA0;
        *(f16x8*)&Ash[ar + 32][ac] = pA1;
        *(f16x8*)&Asl[ar][ac]      = pA2;
        *(f16x8*)&Asl[ar + 32][ac] = pA3;
        #pragma unroll
        for (int j = 0; j < 8; ++j) {
            f16x2 ph; ph[0] = pB0[j]; ph[1] = pB1[j];
            f16x2 pl; pl[0] = pB2[j]; pl[1] = pB3[j];
            *(f16x2*)&Bsh[c8 + j][2 * k2] = ph;
            *(f16x2*)&Bsl[c8 + j][2 * k2] = pl;
        }
        __syncthreads();

        if (k0 + 64 < 2048) {
            const int kn = k0 + 64;
            pA0 = *(const f16x8*)&Abh[(long)ar * 2048 + kn + ac];
            pA1 = *(const f16x8*)&Abh[(long)(ar + 32) * 2048 + kn + ac];
            pA2 = *(const f16x8*)&Abl[(long)ar * 2048 + kn + ac];
            pA3 = *(const f16x8*)&Abl[(long)(ar + 32) * 2048 + kn + ac];
            pB0 = *(const f16x8*)&Bbh[(long)(kn + 2 * k2) * 1536 + c8];
            pB1 = *(const f16x8*)&Bbh[(long)(kn + 2 * k2 + 1) * 1536 + c8];
            pB2 = *(const f16x8*)&Bbl[(long)(kn + 2 * k2) * 1536 + c8];
            pB3 = *(const f16x8*)&Bbl[(long)(kn + 2 * k2 + 1) * 1536 + c8];
        }

        #pragma unroll
        for (int kk = 0; kk < 64; kk += 32) {
            const f16x8 ah0 = *(const f16x8*)&Ash[w * 16 + (L & 15)][kk + kq];
            const f16x8 al0 = *(const f16x8*)&Asl[w * 16 + (L & 15)][kk + kq];
            #pragma unroll
            for (int nt = 0; nt < 4; ++nt) {
                const f16x8 bh = *(const f16x8*)&Bsh[nt * 16 + (L & 15)][kk + kq];
                const f16x8 bl = *(const f16x8*)&Bsl[nt * 16 + (L & 15)][kk + kq];
                acc[nt] = __builtin_amdgcn_mfma_f32_16x16x32_f16(ah0, bh, acc[nt], 0, 0, 0);
                acc[nt] = __builtin_amdgcn_mfma_f32_16x16x32_f16(ah0, bl, acc[nt], 0, 0, 0);
                acc[nt] = __builtin_amdgcn_mfma_f32_16x16x32_f16(al0, bh, acc[nt], 0, 0, 0);
            }
        }
        __syncthreads();
    }

    const int cb = L & 15;
    const int rb = w * 16 + ((L >> 4) << 2);
    #pragma unroll
    for (int r = 0; r < 4; ++r) {
        const float inv = 1.f / lsum[hb * 64 + rb + r];
        #pragma unroll
        for (int nt = 0; nt < 4; ++nt) {
            f16 h, l; split(acc[nt][r] * inv, h, l);
            const long o = ((long)hb * 64 + rb + r) * 1536 + ct * 64 + nt * 16 + cb;
            Uh[o] = h; Ul[o] = l;
        }
    }
}

// ---------------------------------------------------------------------------
// f32 [K,N] -> transposed f16 pair [N,K]
__global__ void k_castTpair(const float* __restrict__ s, f16* __restrict__ dh,
                            f16* __restrict__ dl, int K, int Nn)
{
    const long i = (long)blockIdx.x * 256 + threadIdx.x;
    if (i >= (long)K * Nn) return;
    const int k = (int)(i / Nn), n = (int)(i - (long)k * Nn);
    f16 h, l; split(s[i], h, l);
    dh[(long)n * K + k] = h;
    dl[(long)n * K + k] = l;
}

// normb pair = f16pair( sqrt(sum_f pre^2) + EPS ).  Layout [tok*1536 + f*512 + c]
// (works for both kv_pre [NT toks] and resi_p [512 toks]).
__global__ void k_norm(const f16* __restrict__ kh, const f16* __restrict__ kl,
                       f16* __restrict__ nh, f16* __restrict__ nl)
{
    const long i = (long)blockIdx.x * 256 + threadIdx.x;
    const int tk = (int)(i >> 9), c = (int)(i & 511);
    const long base = (long)tk * 1536 + c;
    const float a = (float)kh[base]        + (float)kl[base];
    const float b = (float)kh[base + 512]  + (float)kl[base + 512];
    const float cc = (float)kh[base + 1024] + (float)kl[base + 1024];
    f16 h, l; split(sqrtf(a * a + b * b + cc * cc) + EPS, h, l);
    nh[i] = h; nl[i] = l;
}

// gate (in-place on kv pair) + kinv pair. One block per token.
__global__ __launch_bounds__(256) void k_gate(
    f16* __restrict__ kh, f16* __restrict__ kl, const float* __restrict__ g,
    f16* __restrict__ kih, f16* __restrict__ kil)
{
    __shared__ float red[3][4];
    const int t = threadIdx.x;
    const int tk = blockIdx.x;
    float kv[2][3];
    float ps0 = 0.f, ps1 = 0.f, ps2 = 0.f;
    #pragma unroll
    for (int j = 0; j < 2; ++j) {
        const int c = t + j * 256;
        const long base = (long)tk * 1536 + c;
        const float k0 = (float)kh[base]        + (float)kl[base];
        const float k1 = (float)kh[base + 512]  + (float)kl[base + 512];
        const float k2 = (float)kh[base + 1024] + (float)kl[base + 1024];
        const float nr = sqrtf(k0 * k0 + k1 * k1 + k2 * k2);
        const float gv = g[(long)tk * 512 + c];
        const float s = (nr <= EPS) ? 1.f : gv / (nr + EPS);
        kv[j][0] = k0 * s; kv[j][1] = k1 * s; kv[j][2] = k2 * s;
        f16 h, l;
        split(kv[j][0], h, l); kh[base] = h;        kl[base] = l;
        split(kv[j][1], h, l); kh[base + 512] = h;  kl[base + 512] = l;
        split(kv[j][2], h, l); kh[base + 1024] = h; kl[base + 1024] = l;
        ps0 += kv[j][0]; ps1 += kv[j][1]; ps2 += kv[j][2];
    }
    for (int off = 32; off; off >>= 1) {
        ps0 += __shfl_down(ps0, off);
        ps1 += __shfl_down(ps1, off);
        ps2 += __shfl_down(ps2, off);
    }
    if ((t & 63) == 0) { red[0][t >> 6] = ps0; red[1][t >> 6] = ps1; red[2][t >> 6] = ps2; }
    __syncthreads();
    const float m0 = (red[0][0] + red[0][1] + red[0][2] + red[0][3]) * (1.f / 512.f);
    const float m1 = (red[1][0] + red[1][1] + red[1][2] + red[1][3]) * (1.f / 512.f);
    const float m2 = (red[2][0] + red[2][1] + red[2][2] + red[2][3]) * (1.f / 512.f);
    #pragma unroll
    for (int j = 0; j < 2; ++j) {
        const int c = t + j * 256;
        f16 h, l; split(kv[j][0] * m0 + kv[j][1] * m1 + kv[j][2] * m2, h, l);
        kih[(long)tk * 512 + c] = h;
        kil[(long)tk * 512 + c] = l;
    }
}

// gate2: out[(tk,f,c)] = resi_p * (g2/(norm+EPS)), fp32 store. One block/token.
__global__ __launch_bounds__(256) void k_gate2(
    const f16* __restrict__ rph, const f16* __restrict__ rpl,
    const float* __restrict__ g2, float* __restrict__ out)
{
    const int t = threadIdx.x;
    const int tk = blockIdx.x;
    #pragma unroll
    for (int j = 0; j < 2; ++j) {
        const int c = t + j * 256;
        const long base = (long)tk * 1536 + c;
        const float r0 = (float)rph[base]        + (float)rpl[base];
        const float r1 = (float)rph[base + 512]  + (float)rpl[base + 512];
        const float r2 = (float)rph[base + 1024] + (float)rpl[base + 1024];
        const float nr = sqrtf(r0 * r0 + r1 * r1 + r2 * r2);
        const float gv = g2[(long)tk * 512 + c];
        const float s = (nr <= EPS) ? 1.f : gv / (nr + EPS);
        out[base]        = r0 * s;
        out[base + 512]  = r1 * s;
        out[base + 1024] = r2 * s;
    }
}

// ---------------------------------------------------------------------------
// q = LN(lq @ wq) per head (fp32 VALU, tiny), output f16 pair [h][qi][64].
__global__ __launch_bounds__(256) void k_qproj(
    const float* __restrict__ lq, const float* __restrict__ wq,
    const float* __restrict__ lns, const float* __restrict__ lnb,
    f16* __restrict__ qh, f16* __restrict__ ql)
{
    __shared__ float cs[QK];
    const int t = threadIdx.x;
    const int qi = blockIdx.x;
    const float* cp = lq + (long)qi * QK;
    for (int i = t; i < QK; i += 256) cs[i] = cp[i];
    __syncthreads();

    float a0 = 0, a1 = 0;
    #pragma unroll 4
    for (int d = 0; d < QK; ++d) {
        const float c = cs[d];
        a0 += c * wq[d * QK + t];
        a1 += c * wq[d * QK + t + 256];
    }
    float s0 = a0, q0 = a0 * a0, s1 = a1, q1 = a1 * a1;
    for (int off = 32; off; off >>= 1) {
        s0 += __shfl_down(s0, off); q0 += __shfl_down(q0, off);
        s1 += __shfl_down(s1, off); q1 += __shfl_down(q1, off);
    }
    s0 = __shfl(s0, 0); q0 = __shfl(q0, 0);
    s1 = __shfl(s1, 0); q1 = __shfl(q1, 0);
    const float mean0 = s0 * (1.f / 64.f), var0 = q0 * (1.f / 64.f) - mean0 * mean0;
    const float mean1 = s1 * (1.f / 64.f), var1 = q1 * (1.f / 64.f) - mean1 * mean1;
    const int e = t & 63;
    const float sc = lns[e], bi = lnb[e];
    const float r0 = (a0 - mean0) * rsqrtf(var0 + LNE) * sc + bi;
    const float r1 = (a1 - mean1) * rsqrtf(var1 + LNE) * sc + bi;
    const int h0 = t >> 6, h1 = h0 + 4;
    f16 h, l;
    split(r0, h, l);
    qh[((long)h0 * Qq + qi) * DH + e] = h;
    ql[((long)h0 * Qq + qi) * DH + e] = l;
    split(r1, h, l);
    qh[((long)h1 * Qq + qi) * DH + e] = h;
    ql[((long)h1 * Qq + qi) * DH + e] = l;
}

// ---------------------------------------------------------------------------
extern "C" void kernel_launch(void* const* d_in, const int* in_sizes, int n_in,
                              void* d_out, int out_size, void* d_ws, size_t ws_size,
                              hipStream_t stream)
{
    const float* x    = (const float*)d_in[0];
    const float* lq   = (const float*)d_in[1];
    const float* w_kv = (const float*)d_in[2];
    const float* w1a  = (const float*)d_in[3];
    const float* b1a  = (const float*)d_in[4];
    const float* w1b  = (const float*)d_in[5];
    const float* b1b  = (const float*)d_in[6];
    const float* wq   = (const float*)d_in[7];
    const float* wk   = (const float*)d_in[8];
    const float* wv   = (const float*)d_in[9];
    const float* lqs  = (const float*)d_in[10];
    const float* lqb  = (const float*)d_in[11];
    const float* lks  = (const float*)d_in[12];
    const float* lkb  = (const float*)d_in[13];
    const float* wo   = (const float*)d_in[14];
    const float* w2a  = (const float*)d_in[15];
    const float* b2a  = (const float*)d_in[16];
    const float* w2b  = (const float*)d_in[17];
    const float* b2b  = (const float*)d_in[18];

    char* ws = (char*)d_ws;
    // Layout (191.5 MB, lifetime-aliased):
    //  W  [0, 3670016): stage-1 weight pairs
    //  S  [3670016, 3817472): qhp | qlp | lsum
    //  W2 [3817472, 5914624): wo/w2a/w2b pairs (stage-2 weights)
    //  A1 [6946816, 40501248): normb pair -> kinv pair -> attn pair -> stage-2 bufs
    //  A2 [40501248, 57278464): hb pair -> resiT f32
    //  B  [57278464, 157941760): kv pair (pre -> gated in-place)
    //  D  [157941760, 191496192): g f32 -> k pair -> U pair
    f16* wkvTh = (f16*)(ws + 0);
    f16* wkvTl = (f16*)(ws + 262144);
    f16* w1aTh = (f16*)(ws + 524288);
    f16* w1aTl = (f16*)(ws + 786432);
    f16* w1bTh = (f16*)(ws + 1048576);
    f16* w1bTl = (f16*)(ws + 1310720);
    f16* wkTh  = (f16*)(ws + 1572864);
    f16* wkTl  = (f16*)(ws + 2097152);
    f16* wvTh  = (f16*)(ws + 2621440);
    f16* wvTl  = (f16*)(ws + 3145728);
    f16*   qhp   = (f16*)(ws + 3670016);
    f16*   qlp   = (f16*)(ws + 3735552);
    float* lsum  = (float*)(ws + 3801088);
    f16* woTh  = (f16*)(ws + 3817472);
    f16* woTl  = (f16*)(ws + 4341760);
    f16* w2aTh = (f16*)(ws + 4866048);
    f16* w2aTl = (f16*)(ws + 5128192);
    f16* w2bTh = (f16*)(ws + 5390336);
    f16* w2bTl = (f16*)(ws + 5652480);
    f16* nh    = (f16*)(ws + 6946816);
    f16* nl    = (f16*)(ws + 23724032);
    f16* kih   = nh;
    f16* kil   = nl;
    f16* ath   = (f16*)(ws + 6946816);
    f16* atl   = (f16*)(ws + 23724032);
    // stage-2 buffers (A1 region; attn dead after step 10)
    f16*   rph  = (f16*)(ws + 6946816);    // 1,572,864
    f16*   rpl  = (f16*)(ws + 8519680);    // 1,572,864
    f16*   n2h  = (f16*)(ws + 10092544);   //   524,288
    f16*   n2l  = (f16*)(ws + 10616832);   //   524,288
    f16*   h2h  = (f16*)(ws + 11141120);   //   262,144
    f16*   h2l  = (f16*)(ws + 11403264);   //   262,144
    float* g2   = (float*)(ws + 11665408); // 1,048,576
    f16* hbh   = (f16*)(ws + 40501248);
    f16* hbl   = (f16*)(ws + 48889856);
    float* resiT = (float*)(ws + 40501248); // aliases hb (dead after step 5)
    f16* kvh   = (f16*)(ws + 57278464);
    f16* kvl   = (f16*)(ws + 107610112);
    float* g    = (float*)(ws + 157941760);
    f16* khb   = (f16*)(ws + 157941760);
    f16* klb   = (f16*)(ws + 174718976);
    f16* Uh    = (f16*)(ws + 157941760);
    f16* Ul    = (f16*)(ws + 170524672);
    float* out  = (float*)d_out;

    // 1. weight casts (transposed pairs)
    k_castTpair<<<512,  256, 0, stream>>>(w_kv, wkvTh, wkvTl, Dd, QK);
    k_castTpair<<<512,  256, 0, stream>>>(w1a,  w1aTh, w1aTl, QK, 256);
    k_castTpair<<<512,  256, 0, stream>>>(w1b,  w1bTh, w1bTl, 256, QK);
    k_castTpair<<<1024, 256, 0, stream>>>(wk,   wkTh,  wkTl,  QK, QK);
    k_castTpair<<<1024, 256, 0, stream>>>(wv,   wvTh,  wvTl,  QK, QK);
    k_castTpair<<<1024, 256, 0, stream>>>(wo,   woTh,  woTl,  Vd, Vd);
    k_castTpair<<<512,  256, 0, stream>>>(w2a,  w2aTh, w2aTl, Vd, 256);
    k_castTpair<<<512,  256, 0, stream>>>(w2b,  w2bTh, w2bTl, 256, Vd);

    // 2. kv_pre = x @ w_kv -> kv pair
    k_gemm3<1, 0><<<dim3(384, 8), 256, 0, stream>>>(
        x, nullptr, nullptr, wkvTh, wkvTl, QK, Dd, kvh, kvl, nullptr, nullptr);
    // 3. norm
    k_norm<<<32768, 256, 0, stream>>>(kvh, kvl, nh, nl);
    // 4. h = leaky(norm @ w1a + b1a) -> hb pair
    k_gemm3<0, 1><<<dim3(128, 4), 256, 0, stream>>>(
        nullptr, nh, nl, w1aTh, w1aTl, 256, QK, hbh, hbl, b1a, nullptr);
    // 5. g = h @ w1b + b1b -> f32
    k_gemm3<0, 2><<<dim3(128, 8), 256, 0, stream>>>(
        nullptr, hbh, hbl, w1bTh, w1bTl, QK, 256, g, nullptr, b1b, nullptr);
    // 6. gate in-place + kinv pair
    k_gate<<<NT, 256, 0, stream>>>(kvh, kvl, g, kih, kil);
    // 7. k = LN(kinv @ wk) -> k pair [h][tok][64]
    k_gemm3<0, 3><<<dim3(128, 8), 256, 0, stream>>>(
        nullptr, kih, kil, wkTh, wkTl, QK, QK, khb, klb, lks, lkb);
    // 8. q -> pair
    k_qproj<<<Qq, 256, 0, stream>>>(lq, wq, lqs, lqb, qhp, qlp);
    // 9. attn: MFMA QK^T + exp + rowsum -> f16 pair (unnormalized)
    k_attn_mfma<<<Hh * B, 256, 0, stream>>>(qhp, qlp, khb, klb, ath, atl, lsum);
    // 10. U = (attn @ kv) / lsum -> U pair (pipelined)
    k_gemm3T<<<64 * 24, 256, 0, stream>>>(ath, atl, kvh, kvl, lsum, Uh, Ul);
    // 11. resi = U @ wv -> resiT f32 [(b,q,f)][512]
    k_gemm3<0, 5><<<dim3(12, 8), 256, 0, stream>>>(
        nullptr, Uh, Ul, wvTh, wvTl, 64, QK, resiT, nullptr, nullptr, nullptr);
    // 12a. resi_p = resiT @ w_out -> pair  [1536,512]
    k_gemm3<1, 0><<<dim3(12, 8), 256, 0, stream>>>(
        resiT, nullptr, nullptr, woTh, woTl, Vd, Vd, rph, rpl, nullptr, nullptr);
    // 12b. norm2 over f (512 tokens)
    k_norm<<<1024, 256, 0, stream>>>(rph, rpl, n2h, n2l);
    // 12c. h2 = leaky(norm2 @ w2a + b2a) -> pair [512,256]
    k_gemm3<0, 1><<<dim3(4, 4), 256, 0, stream>>>(
        nullptr, n2h, n2l, w2aTh, w2aTl, 256, Vd, h2h, h2l, b2a, nullptr);
    // 12d. g2 = h2 @ w2b + b2b -> f32 [512,512]
    k_gemm3<0, 2><<<dim3(4, 8), 256, 0, stream>>>(
        nullptr, h2h, h2l, w2bTh, w2bTl, Vd, 256, g2, nullptr, b2b, nullptr);
    // 12e. out = resi_p * g2/(norm+EPS), fp32
    k_gate2<<<B * Qq, 256, 0, stream>>>(rph, rpl, g2, out);
}